// Round 1
// 7389.746 us; speedup vs baseline: 1.2351x; 1.2351x over previous
//
#include <hip/hip_runtime.h>
#include <hip/hip_bf16.h>
#include <math.h>
#include <stdint.h>

#define B_ 4
#define T_ 1024
#define D_ 1024
#define H_ 16
#define F_ 4096
#define L_ 8
#define NF_ 80
#define E_ 256
#define KW_ 128
#define G_ 16
#define CIN 416       // 2*NF + E
#define DH 64
#define M_ (B_*T_)    // 4096

typedef __attribute__((ext_vector_type(8))) short short8;
typedef __attribute__((ext_vector_type(8))) unsigned short ushort8;
typedef __attribute__((ext_vector_type(4))) float floatx4;

__device__ __forceinline__ float gelu_f(float x) {
    return 0.5f * x * (1.0f + erff(x * 0.70710678118654752f));
}
__device__ __forceinline__ float b2f(unsigned short u) {
    return __uint_as_float(((unsigned int)u) << 16);
}
__device__ __forceinline__ unsigned short f2b(float x) {
    __hip_bfloat16 h = __float2bfloat16(x);
    return *(unsigned short*)&h;
}

// ---------------------------------------------------------------------------
// fp32 -> bf16 convert, 8 elements per thread (n must be multiple of 8)
// ---------------------------------------------------------------------------
__global__ __launch_bounds__(256)
void f2b_kernel(const float* __restrict__ in, __hip_bfloat16* __restrict__ out, int n8)
{
    int i = blockIdx.x * 256 + threadIdx.x;
    if (i >= n8) return;
    const float4* p = (const float4*)in + (size_t)i * 2;
    float4 a = p[0], b = p[1];
    ushort8 r;
    r[0] = f2b(a.x); r[1] = f2b(a.y); r[2] = f2b(a.z); r[3] = f2b(a.w);
    r[4] = f2b(b.x); r[5] = f2b(b.y); r[6] = f2b(b.z); r[7] = f2b(b.w);
    *(ushort8*)((unsigned short*)out + (size_t)i * 8) = r;
}

// ---------------------------------------------------------------------------
// bf16 MFMA GEMM: C[M,N] = post(A@W^T + bias), A (M,K) bf16 row-major
// (optionally split at K1 between A and A2), W (N,K) bf16 row-major.
// 128x128 tile, BK=32, 4 waves, 16x16x32 MFMA, global_load_lds staging.
// Requires M%128==0, N%128==0, K%32==0.
// OUTMODE: 0 = fp32 only, 1 = bf16 only, 2 = both
// ---------------------------------------------------------------------------
template<int ACT, int OUTMODE>
__global__ __launch_bounds__(256)
void mfma_gemm(const __hip_bfloat16* __restrict__ A, const __hip_bfloat16* __restrict__ A2, int K1,
               const __hip_bfloat16* __restrict__ W, const float* __restrict__ bias,
               const float* __restrict__ resid, const float* __restrict__ rowmask,
               float* __restrict__ Cf, __hip_bfloat16* __restrict__ Cb,
               int M, int N, int K, float post_scale)
{
    __shared__ __align__(16) short As[128 * 32];
    __shared__ __align__(16) short Bs[128 * 32];
    const int tid  = threadIdx.x;
    const int lane = tid & 63;
    const int w    = tid >> 6;
    const int wm   = (w & 1) * 64;
    const int wn   = (w >> 1) * 64;
    const int bm   = blockIdx.y * 128;
    const int bn   = blockIdx.x * 128;
    const int lr   = lane >> 2;        // row within 16-row chunk
    const int lc   = (lane & 3) * 8;   // k-element offset of this lane's 16B
    const int fr   = lane & 15;        // fragment row (m or n)
    const int fk   = (lane >> 4) * 8;  // fragment k offset
    const int K2   = K - K1;

    floatx4 acc[4][4] = {};

    for (int k0 = 0; k0 < K; k0 += 32) {
        const int gk = k0 + lc;
        // stage A tile: wave w covers rows [w*32, w*32+32)
#pragma unroll
        for (int j = 0; j < 2; ++j) {
            const int row  = w * 32 + j * 16;
            const int grow = bm + row + lr;
            const __hip_bfloat16* src = (gk < K1)
                ? (A  + (size_t)grow * K1 + gk)
                : (A2 + (size_t)grow * K2 + (gk - K1));
            __builtin_amdgcn_global_load_lds(
                (__attribute__((address_space(1))) void*)(uintptr_t)src,
                (__attribute__((address_space(3))) void*)(uint32_t)(uintptr_t)&As[row * 32],
                16, 0, 0);
        }
        // stage W tile
#pragma unroll
        for (int j = 0; j < 2; ++j) {
            const int row  = w * 32 + j * 16;
            const int grow = bn + row + lr;
            const __hip_bfloat16* src = W + (size_t)grow * K + gk;
            __builtin_amdgcn_global_load_lds(
                (__attribute__((address_space(1))) void*)(uintptr_t)src,
                (__attribute__((address_space(3))) void*)(uint32_t)(uintptr_t)&Bs[row * 32],
                16, 0, 0);
        }
        __syncthreads();

        short8 af[4], bf[4];
#pragma unroll
        for (int mi = 0; mi < 4; ++mi)
            af[mi] = *(const short8*)&As[(wm + mi * 16 + fr) * 32 + fk];
#pragma unroll
        for (int ni = 0; ni < 4; ++ni)
            bf[ni] = *(const short8*)&Bs[(wn + ni * 16 + fr) * 32 + fk];
#pragma unroll
        for (int mi = 0; mi < 4; ++mi)
#pragma unroll
            for (int ni = 0; ni < 4; ++ni)
                acc[mi][ni] = __builtin_amdgcn_mfma_f32_16x16x32_bf16(
                    af[mi], bf[ni], acc[mi][ni], 0, 0, 0);
        __syncthreads();
    }

    // epilogue: C/D layout col = lane&15, row = (lane>>4)*4 + reg
    const int er = (lane >> 4) * 4;
    const int ec = lane & 15;
#pragma unroll
    for (int ni = 0; ni < 4; ++ni) {
        const int col = bn + wn + ni * 16 + ec;
        const float bsv = bias ? bias[col] : 0.f;
#pragma unroll
        for (int mi = 0; mi < 4; ++mi) {
#pragma unroll
            for (int r = 0; r < 4; ++r) {
                const int row = bm + wm + mi * 16 + er + r;
                float v = (acc[mi][ni][r] + bsv) * post_scale;
                if (ACT == 1) v = gelu_f(v);
                if (resid) v += resid[(size_t)row * N + col];
                if (rowmask) v *= rowmask[row];
                if (OUTMODE == 0 || OUTMODE == 2) Cf[(size_t)row * N + col] = v;
                if (OUTMODE == 1 || OUTMODE == 2) Cb[(size_t)row * N + col] = __float2bfloat16(v);
            }
        }
    }
}

// ---------------------------------------------------------------------------
// Generic fp32 GEMM (kept for proj_out, N=80)
// ---------------------------------------------------------------------------
template<int ACT>
__global__ __launch_bounds__(256)
void gemm_kernel(const float* __restrict__ A, const float* __restrict__ A2, int K1,
                 const float* __restrict__ W, const float* __restrict__ bias,
                 const float* __restrict__ resid, const float* __restrict__ rowmask,
                 float* __restrict__ C, int M, int N, int K, float post_scale)
{
    __shared__ float Asm[16][65];
    __shared__ float Wsm[16][132];
    const int tid = threadIdx.x;
    const int tx = tid & 15;
    const int ty = tid >> 4;
    const int bm = blockIdx.y * 64;
    const int bn = blockIdx.x * 128;
    const int lda2 = K - K1;

    float acc[4][8];
#pragma unroll
    for (int i = 0; i < 4; ++i)
#pragma unroll
        for (int j = 0; j < 8; ++j) acc[i][j] = 0.f;

    for (int k0 = 0; k0 < K; k0 += 16) {
#pragma unroll
        for (int l = 0; l < 4; ++l) {
            int e = tid + l * 256;
            int r = e >> 4, c = e & 15;
            int gm = bm + r, gk = k0 + c;
            float v = 0.f;
            if (gm < M && gk < K) {
                v = (gk < K1) ? A[(size_t)gm * K1 + gk]
                              : A2[(size_t)gm * lda2 + (gk - K1)];
            }
            Asm[c][r] = v;
        }
#pragma unroll
        for (int l = 0; l < 8; ++l) {
            int e = tid + l * 256;
            int r = e >> 4, c = e & 15;
            int gn = bn + r, gk = k0 + c;
            float v = 0.f;
            if (gn < N && gk < K) v = W[(size_t)gn * K + gk];
            Wsm[c][r] = v;
        }
        __syncthreads();
#pragma unroll
        for (int kk = 0; kk < 16; ++kk) {
            float a[4], b0[4], b1[4];
#pragma unroll
            for (int i = 0; i < 4; ++i) a[i] = Asm[kk][ty * 4 + i];
#pragma unroll
            for (int j = 0; j < 4; ++j) b0[j] = Wsm[kk][tx * 4 + j];
#pragma unroll
            for (int j = 0; j < 4; ++j) b1[j] = Wsm[kk][64 + tx * 4 + j];
#pragma unroll
            for (int i = 0; i < 4; ++i) {
#pragma unroll
                for (int j = 0; j < 4; ++j) acc[i][j]     += a[i] * b0[j];
#pragma unroll
                for (int j = 0; j < 4; ++j) acc[i][j + 4] += a[i] * b1[j];
            }
        }
        __syncthreads();
    }

#pragma unroll
    for (int i = 0; i < 4; ++i) {
        int gm = bm + ty * 4 + i;
        if (gm >= M) continue;
        float rm = rowmask ? rowmask[gm] : 1.f;
#pragma unroll
        for (int j = 0; j < 8; ++j) {
            int gn = bn + ((j < 4) ? (tx * 4 + j) : (64 + tx * 4 + (j - 4)));
            if (gn >= N) continue;
            float v = acc[i][j];
            if (bias) v += bias[gn];
            v *= post_scale;
            if (ACT == 1) v = gelu_f(v);
            if (resid) v += resid[(size_t)gm * N + gn];
            v *= rm;
            C[(size_t)gm * N + gn] = v;
        }
    }
}

// ---------------------------------------------------------------------------
// Build xin_bf (M, 416) = [x | mu | embed[tokens]] as bf16
// ---------------------------------------------------------------------------
__global__ __launch_bounds__(256)
void xin_kernel(const float* __restrict__ x, const float* __restrict__ mu,
                const int* __restrict__ tokens, const float* __restrict__ emb,
                __hip_bfloat16* __restrict__ xin)
{
    int m = blockIdx.x;
    int b = m >> 10, tt = m & 1023;
    int tok = tokens[m];
    for (int c = threadIdx.x; c < CIN; c += 256) {
        float v;
        if (c < NF_)            v = x[((size_t)b * NF_ + c) * T_ + tt];
        else if (c < 2 * NF_)   v = mu[((size_t)b * NF_ + (c - NF_)) * T_ + tt];
        else                    v = emb[(size_t)tok * E_ + (c - 2 * NF_)];
        xin[(size_t)m * CIN + c] = __float2bfloat16(v);
    }
}

// ---------------------------------------------------------------------------
__global__ __launch_bounds__(256)
void temb_kernel(float* __restrict__ h, const float* __restrict__ t,
                 const float* __restrict__ y_mask)
{
    int m = blockIdx.x;
    int b = m >> 10;
    int d = threadIdx.x * 4;
    float tb = t[b] * 1000.f;
    float rm = y_mask[m];
    float* p = h + (size_t)m * D_ + d;
    float4 v = *(const float4*)p;
    float out[4] = {v.x, v.y, v.z, v.w};
#pragma unroll
    for (int u = 0; u < 4; ++u) {
        int dd = d + u;
        int j = dd & 511;
        float fr = expf((float)j * (-9.210340371976184f / 511.f));
        float ang = tb * fr;
        float e = (dd < 512) ? sinf(ang) : cosf(ang);
        out[u] = (out[u] + e) * rm;
    }
    float4 o; o.x = out[0]; o.y = out[1]; o.z = out[2]; o.w = out[3];
    *(float4*)p = o;
}

// ---------------------------------------------------------------------------
// Build bf16 conv weight panel Wg[d][k*64+i] from posconv_w[dep][d][i][k]
// (one [1024][8192] bf16 matrix per depth; the grouped-conv im2col GEMM's W)
// ---------------------------------------------------------------------------
__global__ __launch_bounds__(256)
void wgtrans_kernel(const float* __restrict__ w, __hip_bfloat16* __restrict__ wg, int dep)
{
    int u = blockIdx.x * 256 + threadIdx.x;   // 1024*128*8 = 1,048,576 units
    int i8 = u & 7;
    int kk = (u >> 3) & 127;
    int d  = u >> 10;
    const float* src = w + (((size_t)dep * D_ + d) * 64 + i8 * 8) * KW_ + kk;
    ushort8 r;
#pragma unroll
    for (int j = 0; j < 8; ++j) r[j] = f2b(src[(size_t)j * KW_]);
    *(ushort8*)((unsigned short*)wg + (size_t)d * 8192 + kk * 64 + i8 * 8) = r;
}

// ---------------------------------------------------------------------------
// Grouped conv1d as implicit-im2col bf16 MFMA GEMM.
// Per block: 128 timesteps x 64 out-channels (one group, one batch).
// Persistent XOR-swizzled input slab (256 rows x 64 ch bf16) in LDS; per tap
// stage the 64x64 weight slice [kc][dl][i32] via global_load_lds; 16 MFMA
// (16x16x32_bf16) per wave per tap. Fused epilogue:
//   hout = hin + gelu(conv + bias) * y_mask   (residual re-read fp32)
// ---------------------------------------------------------------------------
__global__ __launch_bounds__(256)
void convmfma_kernel(const float* __restrict__ hin, float* __restrict__ hout,
                     const __hip_bfloat16* __restrict__ wg, const float* __restrict__ bias,
                     const float* __restrict__ y_mask)
{
    const int t0  = blockIdx.x * 128;
    const int g   = blockIdx.y;
    const int b   = blockIdx.z;
    const int tid = threadIdx.x;
    const int lane = tid & 63;
    const int w    = tid >> 6;
    const int wm   = (w & 1) * 64;       // time offset of wave tile
    const int wn   = (w >> 1) * 32;      // dl offset of wave tile
    const int lr   = lane >> 2;          // staging row within 16
    const int lc   = (lane & 3) * 8;     // staging k-element offset (16B)
    const int fr   = lane & 15;          // fragment row
    const int fk   = (lane >> 4) * 8;    // fragment k offset within 32-chunk

    __shared__ __align__(16) short slab[256 * 64];   // input, XOR-swizzled rows
    __shared__ __align__(16) short Ws[2 * 64 * 32];  // weight tap [kc][dl][i32]

    // ---- stage input slab: rows map to global time t0-64 .. t0+191 ----
    for (int u = tid; u < 2048; u += 256) {
        const int row = u >> 3;             // 0..255
        const int i8  = (u & 7) * 8;        // channel offset
        const int gt  = t0 - 64 + row;
        float4 a = {0.f, 0.f, 0.f, 0.f}, c4 = {0.f, 0.f, 0.f, 0.f};
        if (gt >= 0 && gt < T_) {
            const float* p = hin + ((size_t)(b * T_ + gt) * D_ + g * 64 + i8);
            a  = *(const float4*)p;
            c4 = *(const float4*)(p + 4);
        }
        ushort8 r;
        r[0] = f2b(a.x);  r[1] = f2b(a.y);  r[2] = f2b(a.z);  r[3] = f2b(a.w);
        r[4] = f2b(c4.x); r[5] = f2b(c4.y); r[6] = f2b(c4.z); r[7] = f2b(c4.w);
        const int byte = (row * 128 + i8 * 2) ^ ((row & 7) << 4);
        *(ushort8*)((char*)slab + byte) = r;
    }

    floatx4 acc[4][2] = {};

    for (int tap = 0; tap < 128; ++tap) {
        // stage weight slice for this tap: Wg rows g*64 .. g*64+63, cols tap*64..+64
        {
            const int row = w * 16 + lr;    // 0..63 (dl)
            const __hip_bfloat16* s0 = wg + (size_t)(g * 64 + row) * 8192 + tap * 64 + lc;
            __builtin_amdgcn_global_load_lds(
                (__attribute__((address_space(1))) void*)(uintptr_t)s0,
                (__attribute__((address_space(3))) void*)(uint32_t)(uintptr_t)&Ws[row * 32 + lc],
                16, 0, 0);
            __builtin_amdgcn_global_load_lds(
                (__attribute__((address_space(1))) void*)(uintptr_t)(s0 + 32),
                (__attribute__((address_space(3))) void*)(uint32_t)(uintptr_t)&Ws[2048 + row * 32 + lc],
                16, 0, 0);
        }
        __syncthreads();   // drains gll (and initial slab writes at tap 0)

        short8 af[4][2], bfr[2][2];
#pragma unroll
        for (int mi = 0; mi < 4; ++mi)
#pragma unroll
            for (int kc = 0; kc < 2; ++kc) {
                const int row  = wm + mi * 16 + fr + tap;    // slab row (<= 254)
                const int byte = (row * 128 + (kc * 32 + fk) * 2) ^ ((row & 7) << 4);
                af[mi][kc] = *(const short8*)((const char*)slab + byte);
            }
#pragma unroll
        for (int ni = 0; ni < 2; ++ni)
#pragma unroll
            for (int kc = 0; kc < 2; ++kc)
                bfr[ni][kc] = *(const short8*)&Ws[kc * 2048 + (wn + ni * 16 + fr) * 32 + fk];
#pragma unroll
        for (int mi = 0; mi < 4; ++mi)
#pragma unroll
            for (int ni = 0; ni < 2; ++ni)
#pragma unroll
                for (int kc = 0; kc < 2; ++kc)
                    acc[mi][ni] = __builtin_amdgcn_mfma_f32_16x16x32_bf16(
                        af[mi][kc], bfr[ni][kc], acc[mi][ni], 0, 0, 0);
        __syncthreads();   // protect Ws before next tap's overwrite
    }

    // epilogue: C/D layout col = lane&15, row = (lane>>4)*4 + reg
    const int er = (lane >> 4) * 4;
    const int ec = lane & 15;
#pragma unroll
    for (int ni = 0; ni < 2; ++ni) {
        const int col = g * 64 + wn + ni * 16 + ec;
        const float bsv = bias[col];
#pragma unroll
        for (int mi = 0; mi < 4; ++mi) {
#pragma unroll
            for (int r = 0; r < 4; ++r) {
                const int t = t0 + wm + mi * 16 + er + r;
                const float rm = y_mask[b * T_ + t];
                const size_t idx = (size_t)(b * T_ + t) * D_ + col;
                hout[idx] = hin[idx] + gelu_f(acc[mi][ni][r] + bsv) * rm;
            }
        }
    }
}

// ---------------------------------------------------------------------------
// LayerNorm over D (in-place fp32), optional rowmask, optional bf16 shadow out
// ---------------------------------------------------------------------------
__global__ __launch_bounds__(256)
void ln_kernel(float* __restrict__ X, const float* __restrict__ g,
               const float* __restrict__ bt, const float* __restrict__ rowmask,
               __hip_bfloat16* __restrict__ outbf)
{
    const int m = blockIdx.x;
    const int tid = threadIdx.x;
    const int d = tid * 4;
    float* p = X + (size_t)m * D_ + d;
    float4 v = *(const float4*)p;
    float s  = v.x + v.y + v.z + v.w;
    float s2 = v.x * v.x + v.y * v.y + v.z * v.z + v.w * v.w;
#pragma unroll
    for (int off = 32; off; off >>= 1) {
        s  += __shfl_down(s, off);
        s2 += __shfl_down(s2, off);
    }
    __shared__ float rs[4], rs2[4];
    int wid = tid >> 6;
    if ((tid & 63) == 0) { rs[wid] = s; rs2[wid] = s2; }
    __syncthreads();
    s  = rs[0] + rs[1] + rs[2] + rs[3];
    s2 = rs2[0] + rs2[1] + rs2[2] + rs2[3];
    float mean = s * (1.f / D_);
    float var  = s2 * (1.f / D_) - mean * mean;
    float inv  = rsqrtf(var + 1e-5f);
    float rm = rowmask ? rowmask[m] : 1.f;
    float4 gg = *(const float4*)(g + d);
    float4 bb = *(const float4*)(bt + d);
    float4 o;
    o.x = ((v.x - mean) * inv * gg.x + bb.x) * rm;
    o.y = ((v.y - mean) * inv * gg.y + bb.y) * rm;
    o.z = ((v.z - mean) * inv * gg.z + bb.z) * rm;
    o.w = ((v.w - mean) * inv * gg.w + bb.w) * rm;
    *(float4*)p = o;
    if (outbf) {
        __hip_bfloat16* q = outbf + (size_t)m * D_ + d;
        q[0] = __float2bfloat16(o.x);
        q[1] = __float2bfloat16(o.y);
        q[2] = __float2bfloat16(o.z);
        q[3] = __float2bfloat16(o.w);
    }
}

// ---------------------------------------------------------------------------
// Flash attention v2: 4 lanes per query (16 dims each), 64 queries/block,
// bf16 Q/K/V in, bf16 O out, fp32 math, 64-key LDS tiles.
// ---------------------------------------------------------------------------
__global__ __launch_bounds__(256)
void attn2_kernel(const __hip_bfloat16* __restrict__ Q, const __hip_bfloat16* __restrict__ Kb,
                  const __hip_bfloat16* __restrict__ Vb, const float* __restrict__ y_mask,
                  __hip_bfloat16* __restrict__ O)
{
    const int tid = threadIdx.x;
    const int ql  = tid >> 2;          // query within block
    const int dp  = (tid & 3) * 16;    // dim slice start
    const int qg  = blockIdx.x * 64 + ql;
    const int h   = blockIdx.y;
    const int b   = blockIdx.z;
    const float slope = exp2f(-0.5f * (float)(h + 1));
    __shared__ float Ks[64][68];
    __shared__ float Vs[64][68];

    float qr[16], o[16];
    {
        const ushort4* qp = (const ushort4*)(Q + ((size_t)(b * T_ + qg) * D_ + h * DH + dp));
#pragma unroll
        for (int jj = 0; jj < 4; ++jj) {
            ushort4 u = qp[jj];
            qr[jj * 4 + 0] = b2f(u.x); qr[jj * 4 + 1] = b2f(u.y);
            qr[jj * 4 + 2] = b2f(u.z); qr[jj * 4 + 3] = b2f(u.w);
        }
    }
#pragma unroll
    for (int j = 0; j < 16; ++j) o[j] = 0.f;
    float m = -1e30f, l = 0.f;

    for (int kt = 0; kt < T_; kt += 64) {
        __syncthreads();
        {
            const ushort4* kp = (const ushort4*)(Kb + ((size_t)(b * T_ + kt + ql) * D_ + h * DH + dp));
            const ushort4* vp = (const ushort4*)(Vb + ((size_t)(b * T_ + kt + ql) * D_ + h * DH + dp));
#pragma unroll
            for (int jj = 0; jj < 4; ++jj) {
                ushort4 ku = kp[jj], vu = vp[jj];
                Ks[ql][dp + jj * 4 + 0] = b2f(ku.x); Ks[ql][dp + jj * 4 + 1] = b2f(ku.y);
                Ks[ql][dp + jj * 4 + 2] = b2f(ku.z); Ks[ql][dp + jj * 4 + 3] = b2f(ku.w);
                Vs[ql][dp + jj * 4 + 0] = b2f(vu.x); Vs[ql][dp + jj * 4 + 1] = b2f(vu.y);
                Vs[ql][dp + jj * 4 + 2] = b2f(vu.z); Vs[ql][dp + jj * 4 + 3] = b2f(vu.w);
            }
        }
        __syncthreads();

        for (int c = 0; c < 64; c += 16) {
            float s[16];
            float tmax = -1e30f;
#pragma unroll
            for (int r = 0; r < 16; ++r) {
                int kg = kt + c + r;
                float d = 0.f;
#pragma unroll
                for (int j = 0; j < 16; ++j) d += qr[j] * Ks[c + r][dp + j];
                d += __shfl_xor(d, 1);
                d += __shfl_xor(d, 2);
                d += -slope * fabsf((float)(qg - kg))
                   + (1.f - y_mask[b * T_ + kg]) * (-1e9f);
                s[r] = d;
                tmax = fmaxf(tmax, d);
            }
            float mnew = fmaxf(m, tmax);
            float corr = __expf(m - mnew);
            l *= corr;
#pragma unroll
            for (int j = 0; j < 16; ++j) o[j] *= corr;
#pragma unroll
            for (int r = 0; r < 16; ++r) {
                float p = __expf(s[r] - mnew);
                l += p;
#pragma unroll
                for (int j = 0; j < 16; ++j) o[j] += p * Vs[c + r][dp + j];
            }
            m = mnew;
        }
    }
    float inv = 1.f / l;
    __hip_bfloat16* op = O + ((size_t)(b * T_ + qg) * D_ + h * DH + dp);
#pragma unroll
    for (int j = 0; j < 16; ++j) op[j] = __float2bfloat16(o[j] * inv);
}

// ---------------------------------------------------------------------------
__global__ __launch_bounds__(256)
void outtrans_kernel(const float* __restrict__ tmp, const float* __restrict__ y_mask,
                     float* __restrict__ out)
{
    int e = blockIdx.x * 256 + threadIdx.x;
    if (e >= B_ * NF_ * T_) return;
    int t = e & 1023;
    int f = (e >> 10) % NF_;
    int b = e / (NF_ * T_);
    out[e] = tmp[(size_t)(b * T_ + t) * NF_ + f] * y_mask[b * T_ + t];
}

// ---------------------------------------------------------------------------
static void cvt(const float* w, __hip_bfloat16* dst, size_t n, hipStream_t stream)
{
    int n8 = (int)(n / 8);
    f2b_kernel<<<(n8 + 255) / 256, 256, 0, stream>>>(w, dst, n8);
}

extern "C" void kernel_launch(void* const* d_in, const int* in_sizes, int n_in,
                              void* d_out, int out_size, void* d_ws, size_t ws_size,
                              hipStream_t stream)
{
    const float* x          = (const float*)d_in[0];
    const float* mu         = (const float*)d_in[1];
    const int*   tokens     = (const int*)  d_in[2];
    const float* t_in       = (const float*)d_in[3];
    const float* y_mask     = (const float*)d_in[4];
    const float* emb        = (const float*)d_in[5];
    const float* proj_in_w  = (const float*)d_in[6];
    const float* proj_in_b  = (const float*)d_in[7];
    const float* posconv_w  = (const float*)d_in[8];
    const float* posconv_b  = (const float*)d_in[9];
    const float* ln0_g      = (const float*)d_in[10];
    const float* ln0_b      = (const float*)d_in[11];
    const float* qw         = (const float*)d_in[12];
    const float* qb         = (const float*)d_in[13];
    const float* kw         = (const float*)d_in[14];
    const float* kb         = (const float*)d_in[15];
    const float* vw         = (const float*)d_in[16];
    const float* vb         = (const float*)d_in[17];
    const float* ow         = (const float*)d_in[18];
    const float* ob         = (const float*)d_in[19];
    const float* ln1_g      = (const float*)d_in[20];
    const float* ln1_b      = (const float*)d_in[21];
    const float* ffw1       = (const float*)d_in[22];
    const float* ffb1       = (const float*)d_in[23];
    const float* ffw2       = (const float*)d_in[24];
    const float* ffb2       = (const float*)d_in[25];
    const float* ln2_g      = (const float*)d_in[26];
    const float* ln2_b      = (const float*)d_in[27];
    const float* skw        = (const float*)d_in[28];
    const float* skb        = (const float*)d_in[29];
    const float* pow_       = (const float*)d_in[30];
    const float* pob        = (const float*)d_in[31];

    const size_t MB = (size_t)1 << 20;
    char* wsb = (char*)d_ws;
    float*          hA     = (float*)(wsb + 0);            // 16 MB
    float*          hB     = (float*)(wsb + 16 * MB);      // 16 MB
    __hip_bfloat16* hbfA   = (__hip_bfloat16*)(wsb + 32 * MB);   // 8 MB
    __hip_bfloat16* skipbf = (__hip_bfloat16*)(wsb + 40 * MB);   // 32 MB (4 x 8)
    __hip_bfloat16* q_bf   = (__hip_bfloat16*)(wsb + 72 * MB);   // 8 MB
    __hip_bfloat16* k_bf   = (__hip_bfloat16*)(wsb + 80 * MB);   // 8 MB
    __hip_bfloat16* v_bf   = (__hip_bfloat16*)(wsb + 88 * MB);   // 8 MB
    __hip_bfloat16* o_bf   = (__hip_bfloat16*)(wsb + 96 * MB);   // 8 MB
    __hip_bfloat16* ff_bf  = (__hip_bfloat16*)(wsb + 104 * MB);  // 32 MB
    __hip_bfloat16* wslab  = (__hip_bfloat16*)(wsb + 136 * MB);  // 16 MB
    __hip_bfloat16* hbfB   = (__hip_bfloat16*)(wsb + 152 * MB);  // 8 MB
    // aliases (disjoint lifetimes)
    __hip_bfloat16* wgbf   = (__hip_bfloat16*)(wsb + 104 * MB);  // 16 MB, stem only
    __hip_bfloat16* xin_bf = q_bf;                          // 3.4 MB, stem only
    float*          tmpO   = (float*)(wsb + 72 * MB);      // 1.3 MB, tail only

    const size_t MD = (size_t)M_ * D_;

    dim3 gD(D_ / 128, M_ / 128);   // (8, 32)
    dim3 gF(F_ / 128, M_ / 128);   // (32, 32)

    // ---- stem ----
    xin_kernel<<<M_, 256, 0, stream>>>(x, mu, tokens, emb, xin_bf);
    cvt(proj_in_w, wslab, (size_t)D_ * CIN, stream);
    mfma_gemm<0, 0><<<gD, 256, 0, stream>>>(xin_bf, nullptr, CIN, wslab, proj_in_b,
                                            nullptr, nullptr, hA, nullptr, M_, D_, CIN, 1.f);
    temb_kernel<<<M_, 256, 0, stream>>>(hA, t_in, y_mask);

    wgtrans_kernel<<<4096, 256, 0, stream>>>(posconv_w, wgbf, 0);
    convmfma_kernel<<<dim3(8, 16, 4), 256, 0, stream>>>(hA, hB, wgbf, posconv_b, y_mask);
    wgtrans_kernel<<<4096, 256, 0, stream>>>(posconv_w, wgbf, 1);
    convmfma_kernel<<<dim3(8, 16, 4), 256, 0, stream>>>(hB, hA, wgbf, posconv_b + D_, y_mask);

    ln_kernel<<<M_, 256, 0, stream>>>(hA, ln0_g, ln0_b, nullptr, hbfA);

    float* h = hA;  float* hx = hB;
    __hip_bfloat16* hbf = hbfA;  __hip_bfloat16* hbf_alt = hbfB;

    for (int i = 0; i < L_; ++i) {
        if (i >= L_ / 2) {
            cvt(skw + (size_t)(i - 4) * D_ * 2 * D_, wslab, (size_t)D_ * 2 * D_, stream);
            mfma_gemm<0, 2><<<gD, 256, 0, stream>>>(hbf, skipbf + (size_t)(7 - i) * MD, D_,
                wslab, skb + (size_t)(i - 4) * D_, nullptr, nullptr,
                hx, hbf_alt, M_, D_, 2 * D_, 1.f);
            { float* t0 = h; h = hx; hx = t0; }
            { __hip_bfloat16* t0 = hbf; hbf = hbf_alt; hbf_alt = t0; }
        }
        cvt(qw + (size_t)i * D_ * D_, wslab, (size_t)D_ * D_, stream);
        mfma_gemm<0, 1><<<gD, 256, 0, stream>>>(hbf, nullptr, D_, wslab, qb + (size_t)i * D_,
            nullptr, nullptr, nullptr, q_bf, M_, D_, D_, 0.125f);
        cvt(kw + (size_t)i * D_ * D_, wslab, (size_t)D_ * D_, stream);
        mfma_gemm<0, 1><<<gD, 256, 0, stream>>>(hbf, nullptr, D_, wslab, kb + (size_t)i * D_,
            nullptr, nullptr, nullptr, k_bf, M_, D_, D_, 1.f);
        cvt(vw + (size_t)i * D_ * D_, wslab, (size_t)D_ * D_, stream);
        mfma_gemm<0, 1><<<gD, 256, 0, stream>>>(hbf, nullptr, D_, wslab, vb + (size_t)i * D_,
            nullptr, nullptr, nullptr, v_bf, M_, D_, D_, 1.f);

        attn2_kernel<<<dim3(T_ / 64, H_, B_), 256, 0, stream>>>(q_bf, k_bf, v_bf, y_mask, o_bf);

        cvt(ow + (size_t)i * D_ * D_, wslab, (size_t)D_ * D_, stream);
        mfma_gemm<0, 0><<<gD, 256, 0, stream>>>(o_bf, nullptr, D_, wslab, ob + (size_t)i * D_,
            h, y_mask, hx, nullptr, M_, D_, D_, 1.f);
        { float* t0 = h; h = hx; hx = t0; }

        ln_kernel<<<M_, 256, 0, stream>>>(h, ln1_g + (size_t)i * D_, ln1_b + (size_t)i * D_,
                                          nullptr, hbf);

        cvt(ffw1 + (size_t)i * F_ * D_, wslab, (size_t)F_ * D_, stream);
        mfma_gemm<1, 1><<<gF, 256, 0, stream>>>(hbf, nullptr, D_, wslab, ffb1 + (size_t)i * F_,
            nullptr, nullptr, nullptr, ff_bf, M_, F_, D_, 1.f);
        cvt(ffw2 + (size_t)i * D_ * F_, wslab, (size_t)D_ * F_, stream);
        mfma_gemm<0, 0><<<gD, 256, 0, stream>>>(ff_bf, nullptr, F_, wslab, ffb2 + (size_t)i * D_,
            h, y_mask, hx, nullptr, M_, D_, F_, 1.f);
        { float* t0 = h; h = hx; hx = t0; }

        ln_kernel<<<M_, 256, 0, stream>>>(h, ln2_g + (size_t)i * D_, ln2_b + (size_t)i * D_,
                                          y_mask, hbf);

        if (i < L_ / 2) {
            hipMemcpyAsync(skipbf + (size_t)i * MD, hbf, MD * sizeof(__hip_bfloat16),
                           hipMemcpyDeviceToDevice, stream);
        }
    }

    gemm_kernel<0><<<dim3(1, M_ / 64), 256, 0, stream>>>(h, nullptr, D_, pow_, pob,
        nullptr, nullptr, tmpO, M_, NF_, D_, 1.f);
    outtrans_kernel<<<(B_ * NF_ * T_ + 255) / 256, 256, 0, stream>>>(tmpO, y_mask, (float*)d_out);
}

// Round 2
// 4779.642 us; speedup vs baseline: 1.9096x; 1.5461x over previous
//
#include <hip/hip_runtime.h>
#include <hip/hip_bf16.h>
#include <math.h>
#include <stdint.h>

#define B_ 4
#define T_ 1024
#define D_ 1024
#define H_ 16
#define F_ 4096
#define L_ 8
#define NF_ 80
#define E_ 256
#define KW_ 128
#define G_ 16
#define CIN 416       // 2*NF + E
#define DH 64
#define M_ (B_*T_)    // 4096

typedef __attribute__((ext_vector_type(8))) short short8;
typedef __attribute__((ext_vector_type(8))) unsigned short ushort8;
typedef __attribute__((ext_vector_type(4))) float floatx4;

__device__ __forceinline__ float gelu_f(float x) {
    return 0.5f * x * (1.0f + erff(x * 0.70710678118654752f));
}
__device__ __forceinline__ float b2f(unsigned short u) {
    return __uint_as_float(((unsigned int)u) << 16);
}
__device__ __forceinline__ unsigned short f2b(float x) {
    __hip_bfloat16 h = __float2bfloat16(x);
    return *(unsigned short*)&h;
}

// ---------------------------------------------------------------------------
// fp32 -> bf16 convert, 8 elements per thread (n must be multiple of 8)
// ---------------------------------------------------------------------------
__global__ __launch_bounds__(256)
void f2b_kernel(const float* __restrict__ in, __hip_bfloat16* __restrict__ out, int n8)
{
    int i = blockIdx.x * 256 + threadIdx.x;
    if (i >= n8) return;
    const float4* p = (const float4*)in + (size_t)i * 2;
    float4 a = p[0], b = p[1];
    ushort8 r;
    r[0] = f2b(a.x); r[1] = f2b(a.y); r[2] = f2b(a.z); r[3] = f2b(a.w);
    r[4] = f2b(b.x); r[5] = f2b(b.y); r[6] = f2b(b.z); r[7] = f2b(b.w);
    *(ushort8*)((unsigned short*)out + (size_t)i * 8) = r;
}

// ---------------------------------------------------------------------------
// bf16 MFMA GEMM: C[M,N] = post(A@W^T + bias), A (M,K) bf16 row-major
// (optionally split at K1 between A and A2), W (N,K) bf16 row-major.
// 128x128 tile, BK=32, 4 waves, 16x16x32 MFMA, global_load_lds staging.
// Requires M%128==0, N%128==0, K%32==0.
// OUTMODE: 0 = fp32 only, 1 = bf16 only, 2 = both
// ---------------------------------------------------------------------------
template<int ACT, int OUTMODE>
__global__ __launch_bounds__(256)
void mfma_gemm(const __hip_bfloat16* __restrict__ A, const __hip_bfloat16* __restrict__ A2, int K1,
               const __hip_bfloat16* __restrict__ W, const float* __restrict__ bias,
               const float* __restrict__ resid, const float* __restrict__ rowmask,
               float* __restrict__ Cf, __hip_bfloat16* __restrict__ Cb,
               int M, int N, int K, float post_scale)
{
    __shared__ __align__(16) short As[128 * 32];
    __shared__ __align__(16) short Bs[128 * 32];
    const int tid  = threadIdx.x;
    const int lane = tid & 63;
    const int w    = tid >> 6;
    const int wm   = (w & 1) * 64;
    const int wn   = (w >> 1) * 64;
    const int bm   = blockIdx.y * 128;
    const int bn   = blockIdx.x * 128;
    const int lr   = lane >> 2;        // row within 16-row chunk
    const int lc   = (lane & 3) * 8;   // k-element offset of this lane's 16B
    const int fr   = lane & 15;        // fragment row (m or n)
    const int fk   = (lane >> 4) * 8;  // fragment k offset
    const int K2   = K - K1;

    floatx4 acc[4][4] = {};

    for (int k0 = 0; k0 < K; k0 += 32) {
        const int gk = k0 + lc;
        // stage A tile: wave w covers rows [w*32, w*32+32)
#pragma unroll
        for (int j = 0; j < 2; ++j) {
            const int row  = w * 32 + j * 16;
            const int grow = bm + row + lr;
            const __hip_bfloat16* src = (gk < K1)
                ? (A  + (size_t)grow * K1 + gk)
                : (A2 + (size_t)grow * K2 + (gk - K1));
            __builtin_amdgcn_global_load_lds(
                (__attribute__((address_space(1))) void*)(uintptr_t)src,
                (__attribute__((address_space(3))) void*)(uint32_t)(uintptr_t)&As[row * 32],
                16, 0, 0);
        }
        // stage W tile
#pragma unroll
        for (int j = 0; j < 2; ++j) {
            const int row  = w * 32 + j * 16;
            const int grow = bn + row + lr;
            const __hip_bfloat16* src = W + (size_t)grow * K + gk;
            __builtin_amdgcn_global_load_lds(
                (__attribute__((address_space(1))) void*)(uintptr_t)src,
                (__attribute__((address_space(3))) void*)(uint32_t)(uintptr_t)&Bs[row * 32],
                16, 0, 0);
        }
        __syncthreads();

        short8 af[4], bf[4];
#pragma unroll
        for (int mi = 0; mi < 4; ++mi)
            af[mi] = *(const short8*)&As[(wm + mi * 16 + fr) * 32 + fk];
#pragma unroll
        for (int ni = 0; ni < 4; ++ni)
            bf[ni] = *(const short8*)&Bs[(wn + ni * 16 + fr) * 32 + fk];
#pragma unroll
        for (int mi = 0; mi < 4; ++mi)
#pragma unroll
            for (int ni = 0; ni < 4; ++ni)
                acc[mi][ni] = __builtin_amdgcn_mfma_f32_16x16x32_bf16(
                    af[mi], bf[ni], acc[mi][ni], 0, 0, 0);
        __syncthreads();
    }

    // epilogue: C/D layout col = lane&15, row = (lane>>4)*4 + reg
    const int er = (lane >> 4) * 4;
    const int ec = lane & 15;
#pragma unroll
    for (int ni = 0; ni < 4; ++ni) {
        const int col = bn + wn + ni * 16 + ec;
        const float bsv = bias ? bias[col] : 0.f;
#pragma unroll
        for (int mi = 0; mi < 4; ++mi) {
#pragma unroll
            for (int r = 0; r < 4; ++r) {
                const int row = bm + wm + mi * 16 + er + r;
                float v = (acc[mi][ni][r] + bsv) * post_scale;
                if (ACT == 1) v = gelu_f(v);
                if (resid) v += resid[(size_t)row * N + col];
                if (rowmask) v *= rowmask[row];
                if (OUTMODE == 0 || OUTMODE == 2) Cf[(size_t)row * N + col] = v;
                if (OUTMODE == 1 || OUTMODE == 2) Cb[(size_t)row * N + col] = __float2bfloat16(v);
            }
        }
    }
}

// ---------------------------------------------------------------------------
// Generic fp32 GEMM (kept for proj_out, N=80)
// ---------------------------------------------------------------------------
template<int ACT>
__global__ __launch_bounds__(256)
void gemm_kernel(const float* __restrict__ A, const float* __restrict__ A2, int K1,
                 const float* __restrict__ W, const float* __restrict__ bias,
                 const float* __restrict__ resid, const float* __restrict__ rowmask,
                 float* __restrict__ C, int M, int N, int K, float post_scale)
{
    __shared__ float Asm[16][65];
    __shared__ float Wsm[16][132];
    const int tid = threadIdx.x;
    const int tx = tid & 15;
    const int ty = tid >> 4;
    const int bm = blockIdx.y * 64;
    const int bn = blockIdx.x * 128;
    const int lda2 = K - K1;

    float acc[4][8];
#pragma unroll
    for (int i = 0; i < 4; ++i)
#pragma unroll
        for (int j = 0; j < 8; ++j) acc[i][j] = 0.f;

    for (int k0 = 0; k0 < K; k0 += 16) {
#pragma unroll
        for (int l = 0; l < 4; ++l) {
            int e = tid + l * 256;
            int r = e >> 4, c = e & 15;
            int gm = bm + r, gk = k0 + c;
            float v = 0.f;
            if (gm < M && gk < K) {
                v = (gk < K1) ? A[(size_t)gm * K1 + gk]
                              : A2[(size_t)gm * lda2 + (gk - K1)];
            }
            Asm[c][r] = v;
        }
#pragma unroll
        for (int l = 0; l < 8; ++l) {
            int e = tid + l * 256;
            int r = e >> 4, c = e & 15;
            int gn = bn + r, gk = k0 + c;
            float v = 0.f;
            if (gn < N && gk < K) v = W[(size_t)gn * K + gk];
            Wsm[c][r] = v;
        }
        __syncthreads();
#pragma unroll
        for (int kk = 0; kk < 16; ++kk) {
            float a[4], b0[4], b1[4];
#pragma unroll
            for (int i = 0; i < 4; ++i) a[i] = Asm[kk][ty * 4 + i];
#pragma unroll
            for (int j = 0; j < 4; ++j) b0[j] = Wsm[kk][tx * 4 + j];
#pragma unroll
            for (int j = 0; j < 4; ++j) b1[j] = Wsm[kk][64 + tx * 4 + j];
#pragma unroll
            for (int i = 0; i < 4; ++i) {
#pragma unroll
                for (int j = 0; j < 4; ++j) acc[i][j]     += a[i] * b0[j];
#pragma unroll
                for (int j = 0; j < 4; ++j) acc[i][j + 4] += a[i] * b1[j];
            }
        }
        __syncthreads();
    }

#pragma unroll
    for (int i = 0; i < 4; ++i) {
        int gm = bm + ty * 4 + i;
        if (gm >= M) continue;
        float rm = rowmask ? rowmask[gm] : 1.f;
#pragma unroll
        for (int j = 0; j < 8; ++j) {
            int gn = bn + ((j < 4) ? (tx * 4 + j) : (64 + tx * 4 + (j - 4)));
            if (gn >= N) continue;
            float v = acc[i][j];
            if (bias) v += bias[gn];
            v *= post_scale;
            if (ACT == 1) v = gelu_f(v);
            if (resid) v += resid[(size_t)gm * N + gn];
            v *= rm;
            C[(size_t)gm * N + gn] = v;
        }
    }
}

// ---------------------------------------------------------------------------
// Build xin_bf (M, 416) = [x | mu | embed[tokens]] as bf16
// ---------------------------------------------------------------------------
__global__ __launch_bounds__(256)
void xin_kernel(const float* __restrict__ x, const float* __restrict__ mu,
                const int* __restrict__ tokens, const float* __restrict__ emb,
                __hip_bfloat16* __restrict__ xin)
{
    int m = blockIdx.x;
    int b = m >> 10, tt = m & 1023;
    int tok = tokens[m];
    for (int c = threadIdx.x; c < CIN; c += 256) {
        float v;
        if (c < NF_)            v = x[((size_t)b * NF_ + c) * T_ + tt];
        else if (c < 2 * NF_)   v = mu[((size_t)b * NF_ + (c - NF_)) * T_ + tt];
        else                    v = emb[(size_t)tok * E_ + (c - 2 * NF_)];
        xin[(size_t)m * CIN + c] = __float2bfloat16(v);
    }
}

// ---------------------------------------------------------------------------
__global__ __launch_bounds__(256)
void temb_kernel(float* __restrict__ h, const float* __restrict__ t,
                 const float* __restrict__ y_mask)
{
    int m = blockIdx.x;
    int b = m >> 10;
    int d = threadIdx.x * 4;
    float tb = t[b] * 1000.f;
    float rm = y_mask[m];
    float* p = h + (size_t)m * D_ + d;
    float4 v = *(const float4*)p;
    float out[4] = {v.x, v.y, v.z, v.w};
#pragma unroll
    for (int u = 0; u < 4; ++u) {
        int dd = d + u;
        int j = dd & 511;
        float fr = expf((float)j * (-9.210340371976184f / 511.f));
        float ang = tb * fr;
        float e = (dd < 512) ? sinf(ang) : cosf(ang);
        out[u] = (out[u] + e) * rm;
    }
    float4 o; o.x = out[0]; o.y = out[1]; o.z = out[2]; o.w = out[3];
    *(float4*)p = o;
}

// ---------------------------------------------------------------------------
// Build bf16 conv weight panel Wg[d][k*64+i] from posconv_w[dep][d][i][k]
// ---------------------------------------------------------------------------
__global__ __launch_bounds__(256)
void wgtrans_kernel(const float* __restrict__ w, __hip_bfloat16* __restrict__ wg, int dep)
{
    int u = blockIdx.x * 256 + threadIdx.x;   // 1024*128*8 = 1,048,576 units
    int i8 = u & 7;
    int kk = (u >> 3) & 127;
    int d  = u >> 10;
    const float* src = w + (((size_t)dep * D_ + d) * 64 + i8 * 8) * KW_ + kk;
    ushort8 r;
#pragma unroll
    for (int j = 0; j < 8; ++j) r[j] = f2b(src[(size_t)j * KW_]);
    *(ushort8*)((unsigned short*)wg + (size_t)d * 8192 + kk * 64 + i8 * 8) = r;
}

// ---------------------------------------------------------------------------
// Grouped conv1d as implicit-im2col bf16 MFMA GEMM.
// ---------------------------------------------------------------------------
__global__ __launch_bounds__(256)
void convmfma_kernel(const float* __restrict__ hin, float* __restrict__ hout,
                     const __hip_bfloat16* __restrict__ wg, const float* __restrict__ bias,
                     const float* __restrict__ y_mask)
{
    const int t0  = blockIdx.x * 128;
    const int g   = blockIdx.y;
    const int b   = blockIdx.z;
    const int tid = threadIdx.x;
    const int lane = tid & 63;
    const int w    = tid >> 6;
    const int wm   = (w & 1) * 64;       // time offset of wave tile
    const int wn   = (w >> 1) * 32;      // dl offset of wave tile
    const int lr   = lane >> 2;          // staging row within 16
    const int lc   = (lane & 3) * 8;     // staging k-element offset (16B)
    const int fr   = lane & 15;          // fragment row
    const int fk   = (lane >> 4) * 8;    // fragment k offset within 32-chunk

    __shared__ __align__(16) short slab[256 * 64];   // input, XOR-swizzled rows
    __shared__ __align__(16) short Ws[2 * 64 * 32];  // weight tap [kc][dl][i32]

    for (int u = tid; u < 2048; u += 256) {
        const int row = u >> 3;             // 0..255
        const int i8  = (u & 7) * 8;        // channel offset
        const int gt  = t0 - 64 + row;
        float4 a = {0.f, 0.f, 0.f, 0.f}, c4 = {0.f, 0.f, 0.f, 0.f};
        if (gt >= 0 && gt < T_) {
            const float* p = hin + ((size_t)(b * T_ + gt) * D_ + g * 64 + i8);
            a  = *(const float4*)p;
            c4 = *(const float4*)(p + 4);
        }
        ushort8 r;
        r[0] = f2b(a.x);  r[1] = f2b(a.y);  r[2] = f2b(a.z);  r[3] = f2b(a.w);
        r[4] = f2b(c4.x); r[5] = f2b(c4.y); r[6] = f2b(c4.z); r[7] = f2b(c4.w);
        const int byte = (row * 128 + i8 * 2) ^ ((row & 7) << 4);
        *(ushort8*)((char*)slab + byte) = r;
    }

    floatx4 acc[4][2] = {};

    for (int tap = 0; tap < 128; ++tap) {
        {
            const int row = w * 16 + lr;    // 0..63 (dl)
            const __hip_bfloat16* s0 = wg + (size_t)(g * 64 + row) * 8192 + tap * 64 + lc;
            __builtin_amdgcn_global_load_lds(
                (__attribute__((address_space(1))) void*)(uintptr_t)s0,
                (__attribute__((address_space(3))) void*)(uint32_t)(uintptr_t)&Ws[row * 32 + lc],
                16, 0, 0);
            __builtin_amdgcn_global_load_lds(
                (__attribute__((address_space(1))) void*)(uintptr_t)(s0 + 32),
                (__attribute__((address_space(3))) void*)(uint32_t)(uintptr_t)&Ws[2048 + row * 32 + lc],
                16, 0, 0);
        }
        __syncthreads();

        short8 af[4][2], bfr[2][2];
#pragma unroll
        for (int mi = 0; mi < 4; ++mi)
#pragma unroll
            for (int kc = 0; kc < 2; ++kc) {
                const int row  = wm + mi * 16 + fr + tap;    // slab row (<= 254)
                const int byte = (row * 128 + (kc * 32 + fk) * 2) ^ ((row & 7) << 4);
                af[mi][kc] = *(const short8*)((const char*)slab + byte);
            }
#pragma unroll
        for (int ni = 0; ni < 2; ++ni)
#pragma unroll
            for (int kc = 0; kc < 2; ++kc)
                bfr[ni][kc] = *(const short8*)&Ws[kc * 2048 + (wn + ni * 16 + fr) * 32 + fk];
#pragma unroll
        for (int mi = 0; mi < 4; ++mi)
#pragma unroll
            for (int ni = 0; ni < 2; ++ni)
#pragma unroll
                for (int kc = 0; kc < 2; ++kc)
                    acc[mi][ni] = __builtin_amdgcn_mfma_f32_16x16x32_bf16(
                        af[mi][kc], bfr[ni][kc], acc[mi][ni], 0, 0, 0);
        __syncthreads();
    }

    const int er = (lane >> 4) * 4;
    const int ec = lane & 15;
#pragma unroll
    for (int ni = 0; ni < 2; ++ni) {
        const int col = g * 64 + wn + ni * 16 + ec;
        const float bsv = bias[col];
#pragma unroll
        for (int mi = 0; mi < 4; ++mi) {
#pragma unroll
            for (int r = 0; r < 4; ++r) {
                const int t = t0 + wm + mi * 16 + er + r;
                const float rm = y_mask[b * T_ + t];
                const size_t idx = (size_t)(b * T_ + t) * D_ + col;
                hout[idx] = hin[idx] + gelu_f(acc[mi][ni][r] + bsv) * rm;
            }
        }
    }
}

// ---------------------------------------------------------------------------
// LayerNorm over D (in-place fp32), optional rowmask, optional bf16 shadow out
// ---------------------------------------------------------------------------
__global__ __launch_bounds__(256)
void ln_kernel(float* __restrict__ X, const float* __restrict__ g,
               const float* __restrict__ bt, const float* __restrict__ rowmask,
               __hip_bfloat16* __restrict__ outbf)
{
    const int m = blockIdx.x;
    const int tid = threadIdx.x;
    const int d = tid * 4;
    float* p = X + (size_t)m * D_ + d;
    float4 v = *(const float4*)p;
    float s  = v.x + v.y + v.z + v.w;
    float s2 = v.x * v.x + v.y * v.y + v.z * v.z + v.w * v.w;
#pragma unroll
    for (int off = 32; off; off >>= 1) {
        s  += __shfl_down(s, off);
        s2 += __shfl_down(s2, off);
    }
    __shared__ float rs[4], rs2[4];
    int wid = tid >> 6;
    if ((tid & 63) == 0) { rs[wid] = s; rs2[wid] = s2; }
    __syncthreads();
    s  = rs[0] + rs[1] + rs[2] + rs[3];
    s2 = rs2[0] + rs2[1] + rs2[2] + rs2[3];
    float mean = s * (1.f / D_);
    float var  = s2 * (1.f / D_) - mean * mean;
    float inv  = rsqrtf(var + 1e-5f);
    float rm = rowmask ? rowmask[m] : 1.f;
    float4 gg = *(const float4*)(g + d);
    float4 bb = *(const float4*)(bt + d);
    float4 o;
    o.x = ((v.x - mean) * inv * gg.x + bb.x) * rm;
    o.y = ((v.y - mean) * inv * gg.y + bb.y) * rm;
    o.z = ((v.z - mean) * inv * gg.z + bb.z) * rm;
    o.w = ((v.w - mean) * inv * gg.w + bb.w) * rm;
    *(float4*)p = o;
    if (outbf) {
        __hip_bfloat16* q = outbf + (size_t)m * D_ + d;
        q[0] = __float2bfloat16(o.x);
        q[1] = __float2bfloat16(o.y);
        q[2] = __float2bfloat16(o.z);
        q[3] = __float2bfloat16(o.w);
    }
}

// ---------------------------------------------------------------------------
// MFMA flash attention: one (b,h) per block, 128 queries/block, 4 waves x
// 32 q-rows. KV tiles of 64. bf16 Q/K/V in (Q pre-scaled), bf16 O out.
// K staged via global_load_lds with pre-swizzled source; V staged transposed
// (Vt[d][kv]) with XOR swizzle; P round-trips through per-wave swizzled LDS.
// Swizzle rule everywhere: byte ^= ((row&7)<<4) on 128-byte rows.
// ---------------------------------------------------------------------------
__global__ __launch_bounds__(256)
void attn_mfma_kernel(const __hip_bfloat16* __restrict__ Q, const __hip_bfloat16* __restrict__ Kb,
                      const __hip_bfloat16* __restrict__ Vb, const float* __restrict__ y_mask,
                      __hip_bfloat16* __restrict__ O)
{
    const int tid  = threadIdx.x;
    const int lane = tid & 63;
    const int w    = tid >> 6;
    const int q0   = blockIdx.x * 128;
    const int h    = blockIdx.y;
    const int b    = blockIdx.z;
    const float slope = exp2f(-0.5f * (float)(h + 1));

    __shared__ __align__(16) short Ks[64 * 64];        // [kv][d]  swizzled
    __shared__ __align__(16) short Vt[64 * 64];        // [d][kv]  swizzled
    __shared__ __align__(16) short Ps[4 * 32 * 64];    // per-wave [q][kv] swizzled

    const int g   = lane >> 4;        // 0..3
    const int l15 = lane & 15;
    const int er  = g * 4;            // C-layout row base
    const int ec  = l15;              // C-layout col
    const int wq  = w * 32;           // wave's q offset within block

    // Q fragments (A-layout: row = lane&15, elems = (lane>>4)*8 ..)
    short8 qf[2][2];
#pragma unroll
    for (int m = 0; m < 2; ++m)
#pragma unroll
        for (int kc = 0; kc < 2; ++kc) {
            const size_t off = ((size_t)(b * T_ + q0 + wq + m * 16 + l15) * D_) + h * DH + kc * 32 + g * 8;
            qf[m][kc] = *(const short8*)(Q + off);
        }

    floatx4 oacc[2][4] = {};
    float m_st[2][4], l_st[2][4];
#pragma unroll
    for (int m = 0; m < 2; ++m)
#pragma unroll
        for (int r = 0; r < 4; ++r) { m_st[m][r] = -1e30f; l_st[m][r] = 0.f; }

    short* Pw = &Ps[w * 32 * 64];

    for (int kt = 0; kt < T_; kt += 64) {
        __syncthreads();
        // ---- stage K tile: linear LDS dest, pre-swizzled global source ----
#pragma unroll
        for (int j = 0; j < 2; ++j) {
            const int kv = w * 16 + j * 8 + (lane >> 3);
            const int c  = lane & 7;
            const int sw = ((lane >> 3) & 7) << 4;          // (kv&7)<<4
            const __hip_bfloat16* src = Kb + ((size_t)(b * T_ + kt + kv) * D_ + h * DH)
                                          + ((((c * 16) ^ sw)) >> 1);
            __builtin_amdgcn_global_load_lds(
                (__attribute__((address_space(1))) void*)(uintptr_t)src,
                (__attribute__((address_space(3))) void*)(uint32_t)(uintptr_t)&Ks[(w * 16 + j * 8) * 64],
                16, 0, 0);
        }
        // ---- stage V transposed: Vt[d][kv], packed pair writes ----
        {
            const int kv0 = (tid & 31) * 2;
            const int d0  = (tid >> 5) * 8;
            ushort8 va  = *(const ushort8*)(Vb + ((size_t)(b * T_ + kt + kv0    ) * D_ + h * DH + d0));
            ushort8 vb8 = *(const ushort8*)(Vb + ((size_t)(b * T_ + kt + kv0 + 1) * D_ + h * DH + d0));
#pragma unroll
            for (int j = 0; j < 8; ++j) {
                const int d = d0 + j;
                const int byte = ((d * 128 + kv0 * 2) ^ ((d & 7) << 4));
                unsigned int pk = (unsigned int)va[j] | ((unsigned int)vb8[j] << 16);
                *(unsigned int*)((char*)Vt + byte) = pk;
            }
        }
        __syncthreads();

        // ---- QK^T: S (32q x 64kv) per wave ----
        floatx4 sacc[2][4] = {};
#pragma unroll
        for (int kc = 0; kc < 2; ++kc) {
            short8 kf[4];
#pragma unroll
            for (int n = 0; n < 4; ++n) {
                const int kv = n * 16 + l15;
                const int byte = ((kv * 128 + (kc * 32 + g * 8) * 2) ^ ((kv & 7) << 4));
                kf[n] = *(const short8*)((const char*)Ks + byte);
            }
#pragma unroll
            for (int m = 0; m < 2; ++m)
#pragma unroll
                for (int n = 0; n < 4; ++n)
                    sacc[m][n] = __builtin_amdgcn_mfma_f32_16x16x32_bf16(
                        qf[m][kc], kf[n], sacc[m][n], 0, 0, 0);
        }

        float ymv[4];
#pragma unroll
        for (int n = 0; n < 4; ++n)
            ymv[n] = (1.f - y_mask[b * T_ + kt + n * 16 + ec]) * (-1e9f);

        // ---- bias + online softmax (row across 16 lanes, shfl_xor reduce) ----
#pragma unroll
        for (int m = 0; m < 2; ++m) {
#pragma unroll
            for (int r = 0; r < 4; ++r) {
                const float qgf = (float)(q0 + wq + m * 16 + er + r);
                float sv[4];
                float rowmax = -1e30f;
#pragma unroll
                for (int n = 0; n < 4; ++n) {
                    const float kgf = (float)(kt + n * 16 + ec);
                    float s = sacc[m][n][r] - slope * fabsf(qgf - kgf) + ymv[n];
                    sv[n] = s;
                    rowmax = fmaxf(rowmax, s);
                }
#pragma unroll
                for (int off = 1; off < 16; off <<= 1)
                    rowmax = fmaxf(rowmax, __shfl_xor(rowmax, off));
                const float mn   = fmaxf(m_st[m][r], rowmax);
                const float corr = __expf(m_st[m][r] - mn);
                m_st[m][r] = mn;
                float psum = 0.f;
#pragma unroll
                for (int n = 0; n < 4; ++n) {
                    float p = __expf(sv[n] - mn);
                    psum += p;
                    sacc[m][n][r] = p;
                }
#pragma unroll
                for (int off = 1; off < 16; off <<= 1)
                    psum += __shfl_xor(psum, off);
                l_st[m][r] = l_st[m][r] * corr + psum;
#pragma unroll
                for (int n = 0; n < 4; ++n)
                    oacc[m][n][r] *= corr;
            }
        }

        // ---- P -> bf16 -> per-wave swizzled LDS ----
#pragma unroll
        for (int m = 0; m < 2; ++m)
#pragma unroll
            for (int n = 0; n < 4; ++n)
#pragma unroll
                for (int r = 0; r < 4; ++r) {
                    const int ql = m * 16 + er + r;
                    const int kv = n * 16 + ec;
                    const int byte = ((ql * 128 + kv * 2) ^ ((ql & 7) << 4));
                    *(unsigned short*)((char*)Pw + byte) = f2b(sacc[m][n][r]);
                }

        // ---- PV: O += P @ V ----
#pragma unroll
        for (int kc = 0; kc < 2; ++kc) {
            short8 pf[2], vf[4];
#pragma unroll
            for (int m = 0; m < 2; ++m) {
                const int ql = m * 16 + l15;
                const int byte = ((ql * 128 + (kc * 32 + g * 8) * 2) ^ ((ql & 7) << 4));
                pf[m] = *(const short8*)((const char*)Pw + byte);
            }
#pragma unroll
            for (int n = 0; n < 4; ++n) {
                const int d = n * 16 + l15;
                const int byte = ((d * 128 + (kc * 32 + g * 8) * 2) ^ ((d & 7) << 4));
                vf[n] = *(const short8*)((const char*)Vt + byte);
            }
#pragma unroll
            for (int m = 0; m < 2; ++m)
#pragma unroll
                for (int n = 0; n < 4; ++n)
                    oacc[m][n] = __builtin_amdgcn_mfma_f32_16x16x32_bf16(
                        pf[m], vf[n], oacc[m][n], 0, 0, 0);
        }
    }

    // ---- epilogue: O * (1/l) -> bf16 ----
#pragma unroll
    for (int m = 0; m < 2; ++m) {
#pragma unroll
        for (int r = 0; r < 4; ++r) {
            const float inv = 1.f / l_st[m][r];
            const int qg = q0 + wq + m * 16 + er + r;
#pragma unroll
            for (int n = 0; n < 4; ++n) {
                O[((size_t)(b * T_ + qg) * D_) + h * DH + n * 16 + ec] =
                    __float2bfloat16(oacc[m][n][r] * inv);
            }
        }
    }
}

// ---------------------------------------------------------------------------
__global__ __launch_bounds__(256)
void outtrans_kernel(const float* __restrict__ tmp, const float* __restrict__ y_mask,
                     float* __restrict__ out)
{
    int e = blockIdx.x * 256 + threadIdx.x;
    if (e >= B_ * NF_ * T_) return;
    int t = e & 1023;
    int f = (e >> 10) % NF_;
    int b = e / (NF_ * T_);
    out[e] = tmp[(size_t)(b * T_ + t) * NF_ + f] * y_mask[b * T_ + t];
}

// ---------------------------------------------------------------------------
static void cvt(const float* w, __hip_bfloat16* dst, size_t n, hipStream_t stream)
{
    int n8 = (int)(n / 8);
    f2b_kernel<<<(n8 + 255) / 256, 256, 0, stream>>>(w, dst, n8);
}

extern "C" void kernel_launch(void* const* d_in, const int* in_sizes, int n_in,
                              void* d_out, int out_size, void* d_ws, size_t ws_size,
                              hipStream_t stream)
{
    const float* x          = (const float*)d_in[0];
    const float* mu         = (const float*)d_in[1];
    const int*   tokens     = (const int*)  d_in[2];
    const float* t_in       = (const float*)d_in[3];
    const float* y_mask     = (const float*)d_in[4];
    const float* emb        = (const float*)d_in[5];
    const float* proj_in_w  = (const float*)d_in[6];
    const float* proj_in_b  = (const float*)d_in[7];
    const float* posconv_w  = (const float*)d_in[8];
    const float* posconv_b  = (const float*)d_in[9];
    const float* ln0_g      = (const float*)d_in[10];
    const float* ln0_b      = (const float*)d_in[11];
    const float* qw         = (const float*)d_in[12];
    const float* qb         = (const float*)d_in[13];
    const float* kw         = (const float*)d_in[14];
    const float* kb         = (const float*)d_in[15];
    const float* vw         = (const float*)d_in[16];
    const float* vb         = (const float*)d_in[17];
    const float* ow         = (const float*)d_in[18];
    const float* ob         = (const float*)d_in[19];
    const float* ln1_g      = (const float*)d_in[20];
    const float* ln1_b      = (const float*)d_in[21];
    const float* ffw1       = (const float*)d_in[22];
    const float* ffb1       = (const float*)d_in[23];
    const float* ffw2       = (const float*)d_in[24];
    const float* ffb2       = (const float*)d_in[25];
    const float* ln2_g      = (const float*)d_in[26];
    const float* ln2_b      = (const float*)d_in[27];
    const float* skw        = (const float*)d_in[28];
    const float* skb        = (const float*)d_in[29];
    const float* pow_       = (const float*)d_in[30];
    const float* pob        = (const float*)d_in[31];

    const size_t MB = (size_t)1 << 20;
    char* wsb = (char*)d_ws;
    float*          hA     = (float*)(wsb + 0);            // 16 MB
    float*          hB     = (float*)(wsb + 16 * MB);      // 16 MB
    __hip_bfloat16* hbfA   = (__hip_bfloat16*)(wsb + 32 * MB);   // 8 MB
    __hip_bfloat16* skipbf = (__hip_bfloat16*)(wsb + 40 * MB);   // 32 MB (4 x 8)
    __hip_bfloat16* q_bf   = (__hip_bfloat16*)(wsb + 72 * MB);   // 8 MB
    __hip_bfloat16* k_bf   = (__hip_bfloat16*)(wsb + 80 * MB);   // 8 MB
    __hip_bfloat16* v_bf   = (__hip_bfloat16*)(wsb + 88 * MB);   // 8 MB
    __hip_bfloat16* o_bf   = (__hip_bfloat16*)(wsb + 96 * MB);   // 8 MB
    __hip_bfloat16* ff_bf  = (__hip_bfloat16*)(wsb + 104 * MB);  // 32 MB
    __hip_bfloat16* wslab  = (__hip_bfloat16*)(wsb + 136 * MB);  // 16 MB
    __hip_bfloat16* hbfB   = (__hip_bfloat16*)(wsb + 152 * MB);  // 8 MB
    // aliases (disjoint lifetimes)
    __hip_bfloat16* wgbf   = (__hip_bfloat16*)(wsb + 104 * MB);  // 16 MB, stem only
    __hip_bfloat16* xin_bf = q_bf;                          // 3.4 MB, stem only
    float*          tmpO   = (float*)(wsb + 72 * MB);      // 1.3 MB, tail only

    const size_t MD = (size_t)M_ * D_;

    dim3 gD(D_ / 128, M_ / 128);   // (8, 32)
    dim3 gF(F_ / 128, M_ / 128);   // (32, 32)

    // ---- stem ----
    xin_kernel<<<M_, 256, 0, stream>>>(x, mu, tokens, emb, xin_bf);
    cvt(proj_in_w, wslab, (size_t)D_ * CIN, stream);
    mfma_gemm<0, 0><<<gD, 256, 0, stream>>>(xin_bf, nullptr, CIN, wslab, proj_in_b,
                                            nullptr, nullptr, hA, nullptr, M_, D_, CIN, 1.f);
    temb_kernel<<<M_, 256, 0, stream>>>(hA, t_in, y_mask);

    wgtrans_kernel<<<4096, 256, 0, stream>>>(posconv_w, wgbf, 0);
    convmfma_kernel<<<dim3(8, 16, 4), 256, 0, stream>>>(hA, hB, wgbf, posconv_b, y_mask);
    wgtrans_kernel<<<4096, 256, 0, stream>>>(posconv_w, wgbf, 1);
    convmfma_kernel<<<dim3(8, 16, 4), 256, 0, stream>>>(hB, hA, wgbf, posconv_b + D_, y_mask);

    ln_kernel<<<M_, 256, 0, stream>>>(hA, ln0_g, ln0_b, nullptr, hbfA);

    float* h = hA;  float* hx = hB;
    __hip_bfloat16* hbf = hbfA;  __hip_bfloat16* hbf_alt = hbfB;

    for (int i = 0; i < L_; ++i) {
        if (i >= L_ / 2) {
            cvt(skw + (size_t)(i - 4) * D_ * 2 * D_, wslab, (size_t)D_ * 2 * D_, stream);
            mfma_gemm<0, 2><<<gD, 256, 0, stream>>>(hbf, skipbf + (size_t)(7 - i) * MD, D_,
                wslab, skb + (size_t)(i - 4) * D_, nullptr, nullptr,
                hx, hbf_alt, M_, D_, 2 * D_, 1.f);
            { float* t0 = h; h = hx; hx = t0; }
            { __hip_bfloat16* t0 = hbf; hbf = hbf_alt; hbf_alt = t0; }
        }
        cvt(qw + (size_t)i * D_ * D_, wslab, (size_t)D_ * D_, stream);
        mfma_gemm<0, 1><<<gD, 256, 0, stream>>>(hbf, nullptr, D_, wslab, qb + (size_t)i * D_,
            nullptr, nullptr, nullptr, q_bf, M_, D_, D_, 0.125f);
        cvt(kw + (size_t)i * D_ * D_, wslab, (size_t)D_ * D_, stream);
        mfma_gemm<0, 1><<<gD, 256, 0, stream>>>(hbf, nullptr, D_, wslab, kb + (size_t)i * D_,
            nullptr, nullptr, nullptr, k_bf, M_, D_, D_, 1.f);
        cvt(vw + (size_t)i * D_ * D_, wslab, (size_t)D_ * D_, stream);
        mfma_gemm<0, 1><<<gD, 256, 0, stream>>>(hbf, nullptr, D_, wslab, vb + (size_t)i * D_,
            nullptr, nullptr, nullptr, v_bf, M_, D_, D_, 1.f);

        attn_mfma_kernel<<<dim3(T_ / 128, H_, B_), 256, 0, stream>>>(q_bf, k_bf, v_bf, y_mask, o_bf);

        cvt(ow + (size_t)i * D_ * D_, wslab, (size_t)D_ * D_, stream);
        mfma_gemm<0, 0><<<gD, 256, 0, stream>>>(o_bf, nullptr, D_, wslab, ob + (size_t)i * D_,
            h, y_mask, hx, nullptr, M_, D_, D_, 1.f);
        { float* t0 = h; h = hx; hx = t0; }

        ln_kernel<<<M_, 256, 0, stream>>>(h, ln1_g + (size_t)i * D_, ln1_b + (size_t)i * D_,
                                          nullptr, hbf);

        cvt(ffw1 + (size_t)i * F_ * D_, wslab, (size_t)F_ * D_, stream);
        mfma_gemm<1, 1><<<gF, 256, 0, stream>>>(hbf, nullptr, D_, wslab, ffb1 + (size_t)i * F_,
            nullptr, nullptr, nullptr, ff_bf, M_, F_, D_, 1.f);
        cvt(ffw2 + (size_t)i * D_ * F_, wslab, (size_t)D_ * F_, stream);
        mfma_gemm<0, 0><<<gD, 256, 0, stream>>>(ff_bf, nullptr, F_, wslab, ffb2 + (size_t)i * D_,
            h, y_mask, hx, nullptr, M_, D_, F_, 1.f);
        { float* t0 = h; h = hx; hx = t0; }

        ln_kernel<<<M_, 256, 0, stream>>>(h, ln2_g + (size_t)i * D_, ln2_b + (size_t)i * D_,
                                          y_mask, hbf);

        if (i < L_ / 2) {
            hipMemcpyAsync(skipbf + (size_t)i * MD, hbf, MD * sizeof(__hip_bfloat16),
                           hipMemcpyDeviceToDevice, stream);
        }
    }

    gemm_kernel<0><<<dim3(1, M_ / 64), 256, 0, stream>>>(h, nullptr, D_, pow_, pob,
        nullptr, nullptr, tmpO, M_, NF_, D_, 1.f);
    outtrans_kernel<<<(B_ * NF_ * T_ + 255) / 256, 256, 0, stream>>>(tmpO, y_mask, (float*)d_out);
}

// Round 3
// 3750.267 us; speedup vs baseline: 2.4338x; 1.2745x over previous
//
#include <hip/hip_runtime.h>
#include <hip/hip_bf16.h>
#include <math.h>
#include <stdint.h>

#define B_ 4
#define T_ 1024
#define D_ 1024
#define H_ 16
#define F_ 4096
#define L_ 8
#define NF_ 80
#define E_ 256
#define KW_ 128
#define G_ 16
#define CIN 416       // 2*NF + E
#define DH 64
#define M_ (B_*T_)    // 4096

typedef __attribute__((ext_vector_type(8))) short short8;
typedef __attribute__((ext_vector_type(8))) unsigned short ushort8;
typedef __attribute__((ext_vector_type(4))) float floatx4;

__device__ __forceinline__ float gelu_f(float x) {
    return 0.5f * x * (1.0f + erff(x * 0.70710678118654752f));
}
__device__ __forceinline__ float b2f(unsigned short u) {
    return __uint_as_float(((unsigned int)u) << 16);
}
__device__ __forceinline__ unsigned short f2b(float x) {
    __hip_bfloat16 h = __float2bfloat16(x);
    return *(unsigned short*)&h;
}

// ---------------------------------------------------------------------------
// fp32 -> bf16 convert, 8 elements per thread (n must be multiple of 8)
// ---------------------------------------------------------------------------
__global__ __launch_bounds__(256)
void f2b_kernel(const float* __restrict__ in, __hip_bfloat16* __restrict__ out, int n8)
{
    int i = blockIdx.x * 256 + threadIdx.x;
    if (i >= n8) return;
    const float4* p = (const float4*)in + (size_t)i * 2;
    float4 a = p[0], b = p[1];
    ushort8 r;
    r[0] = f2b(a.x); r[1] = f2b(a.y); r[2] = f2b(a.z); r[3] = f2b(a.w);
    r[4] = f2b(b.x); r[5] = f2b(b.y); r[6] = f2b(b.z); r[7] = f2b(b.w);
    *(ushort8*)((unsigned short*)out + (size_t)i * 8) = r;
}

// ---------------------------------------------------------------------------
// bf16 MFMA GEMM: C[M,N] = post(A@W^T + bias), A (M,K) bf16 row-major
// (optionally split at K1 between A and A2), W (N,K) bf16 row-major.
// BMxBN=BMx128 tile (BM = 128 or 64), BK=32, 4 waves, 16x16x32 MFMA,
// global_load_lds staging. Requires M%BM==0, N%128==0, K%32==0.
// OUTMODE: 0 = fp32 only, 1 = bf16 only, 2 = both
// ---------------------------------------------------------------------------
template<int ACT, int OUTMODE, int BM>
__global__ __launch_bounds__(256)
void mfma_gemm(const __hip_bfloat16* __restrict__ A, const __hip_bfloat16* __restrict__ A2, int K1,
               const __hip_bfloat16* __restrict__ W, const float* __restrict__ bias,
               const float* __restrict__ resid, const float* __restrict__ rowmask,
               float* __restrict__ Cf, __hip_bfloat16* __restrict__ Cb,
               int M, int N, int K, float post_scale)
{
    constexpr int MI = BM / 32;          // m-fragments per wave (4 or 2)
    __shared__ __align__(16) short As[BM * 32];
    __shared__ __align__(16) short Bs[128 * 32];
    const int tid  = threadIdx.x;
    const int lane = tid & 63;
    const int w    = tid >> 6;
    const int wm   = (w & 1) * (BM / 2);
    const int wn   = (w >> 1) * 64;
    const int bm   = blockIdx.y * BM;
    const int bn   = blockIdx.x * 128;
    const int lr   = lane >> 2;        // row within 16-row chunk
    const int lc   = (lane & 3) * 8;   // k-element offset of this lane's 16B
    const int fr   = lane & 15;        // fragment row (m or n)
    const int fk   = (lane >> 4) * 8;  // fragment k offset
    const int K2   = K - K1;

    floatx4 acc[MI][4] = {};

    for (int k0 = 0; k0 < K; k0 += 32) {
        const int gk = k0 + lc;
        // stage A tile: BM rows, each wave covers BM/4 rows
#pragma unroll
        for (int j = 0; j < BM / 64; ++j) {
            const int row  = w * (BM / 4) + j * 16;
            const int grow = bm + row + lr;
            const __hip_bfloat16* src = (gk < K1)
                ? (A  + (size_t)grow * K1 + gk)
                : (A2 + (size_t)grow * K2 + (gk - K1));
            __builtin_amdgcn_global_load_lds(
                (__attribute__((address_space(1))) void*)(uintptr_t)src,
                (__attribute__((address_space(3))) void*)(uint32_t)(uintptr_t)&As[row * 32],
                16, 0, 0);
        }
        // stage W tile (always 128 rows)
#pragma unroll
        for (int j = 0; j < 2; ++j) {
            const int row  = w * 32 + j * 16;
            const int grow = bn + row + lr;
            const __hip_bfloat16* src = W + (size_t)grow * K + gk;
            __builtin_amdgcn_global_load_lds(
                (__attribute__((address_space(1))) void*)(uintptr_t)src,
                (__attribute__((address_space(3))) void*)(uint32_t)(uintptr_t)&Bs[row * 32],
                16, 0, 0);
        }
        __syncthreads();

        short8 af[MI], bf[4];
#pragma unroll
        for (int mi = 0; mi < MI; ++mi)
            af[mi] = *(const short8*)&As[(wm + mi * 16 + fr) * 32 + fk];
#pragma unroll
        for (int ni = 0; ni < 4; ++ni)
            bf[ni] = *(const short8*)&Bs[(wn + ni * 16 + fr) * 32 + fk];
#pragma unroll
        for (int mi = 0; mi < MI; ++mi)
#pragma unroll
            for (int ni = 0; ni < 4; ++ni)
                acc[mi][ni] = __builtin_amdgcn_mfma_f32_16x16x32_bf16(
                    af[mi], bf[ni], acc[mi][ni], 0, 0, 0);
        __syncthreads();
    }

    // epilogue: C/D layout col = lane&15, row = (lane>>4)*4 + reg
    const int er = (lane >> 4) * 4;
    const int ec = lane & 15;
#pragma unroll
    for (int ni = 0; ni < 4; ++ni) {
        const int col = bn + wn + ni * 16 + ec;
        const float bsv = bias ? bias[col] : 0.f;
#pragma unroll
        for (int mi = 0; mi < MI; ++mi) {
#pragma unroll
            for (int r = 0; r < 4; ++r) {
                const int row = bm + wm + mi * 16 + er + r;
                float v = (acc[mi][ni][r] + bsv) * post_scale;
                if (ACT == 1) v = gelu_f(v);
                if (resid) v += resid[(size_t)row * N + col];
                if (rowmask) v *= rowmask[row];
                if (OUTMODE == 0 || OUTMODE == 2) Cf[(size_t)row * N + col] = v;
                if (OUTMODE == 1 || OUTMODE == 2) Cb[(size_t)row * N + col] = __float2bfloat16(v);
            }
        }
    }
}

// ---------------------------------------------------------------------------
// Build xin_bf (M, 416) = [x | mu | embed[tokens]] as bf16
// ---------------------------------------------------------------------------
__global__ __launch_bounds__(256)
void xin_kernel(const float* __restrict__ x, const float* __restrict__ mu,
                const int* __restrict__ tokens, const float* __restrict__ emb,
                __hip_bfloat16* __restrict__ xin)
{
    int m = blockIdx.x;
    int b = m >> 10, tt = m & 1023;
    int tok = tokens[m];
    for (int c = threadIdx.x; c < CIN; c += 256) {
        float v;
        if (c < NF_)            v = x[((size_t)b * NF_ + c) * T_ + tt];
        else if (c < 2 * NF_)   v = mu[((size_t)b * NF_ + (c - NF_)) * T_ + tt];
        else                    v = emb[(size_t)tok * E_ + (c - 2 * NF_)];
        xin[(size_t)m * CIN + c] = __float2bfloat16(v);
    }
}

// ---------------------------------------------------------------------------
__global__ __launch_bounds__(256)
void temb_kernel(float* __restrict__ h, const float* __restrict__ t,
                 const float* __restrict__ y_mask)
{
    int m = blockIdx.x;
    int b = m >> 10;
    int d = threadIdx.x * 4;
    float tb = t[b] * 1000.f;
    float rm = y_mask[m];
    float* p = h + (size_t)m * D_ + d;
    float4 v = *(const float4*)p;
    float out[4] = {v.x, v.y, v.z, v.w};
#pragma unroll
    for (int u = 0; u < 4; ++u) {
        int dd = d + u;
        int j = dd & 511;
        float fr = expf((float)j * (-9.210340371976184f / 511.f));
        float ang = tb * fr;
        float e = (dd < 512) ? sinf(ang) : cosf(ang);
        out[u] = (out[u] + e) * rm;
    }
    float4 o; o.x = out[0]; o.y = out[1]; o.z = out[2]; o.w = out[3];
    *(float4*)p = o;
}

// ---------------------------------------------------------------------------
// Build bf16 conv weight panel Wg[d][k*64+i] from posconv_w[dep][d][i][k]
// ---------------------------------------------------------------------------
__global__ __launch_bounds__(256)
void wgtrans_kernel(const float* __restrict__ w, __hip_bfloat16* __restrict__ wg, int dep)
{
    int u = blockIdx.x * 256 + threadIdx.x;   // 1024*128*8 = 1,048,576 units
    int i8 = u & 7;
    int kk = (u >> 3) & 127;
    int d  = u >> 10;
    const float* src = w + (((size_t)dep * D_ + d) * 64 + i8 * 8) * KW_ + kk;
    ushort8 r;
#pragma unroll
    for (int j = 0; j < 8; ++j) r[j] = f2b(src[(size_t)j * KW_]);
    *(ushort8*)((unsigned short*)wg + (size_t)d * 8192 + kk * 64 + i8 * 8) = r;
}

// ---------------------------------------------------------------------------
// Grouped conv1d as implicit-im2col bf16 MFMA GEMM.
// ---------------------------------------------------------------------------
__global__ __launch_bounds__(256)
void convmfma_kernel(const float* __restrict__ hin, float* __restrict__ hout,
                     const __hip_bfloat16* __restrict__ wg, const float* __restrict__ bias,
                     const float* __restrict__ y_mask)
{
    const int t0  = blockIdx.x * 128;
    const int g   = blockIdx.y;
    const int b   = blockIdx.z;
    const int tid = threadIdx.x;
    const int lane = tid & 63;
    const int w    = tid >> 6;
    const int wm   = (w & 1) * 64;       // time offset of wave tile
    const int wn   = (w >> 1) * 32;      // dl offset of wave tile
    const int lr   = lane >> 2;          // staging row within 16
    const int lc   = (lane & 3) * 8;     // staging k-element offset (16B)
    const int fr   = lane & 15;          // fragment row
    const int fk   = (lane >> 4) * 8;    // fragment k offset within 32-chunk

    __shared__ __align__(16) short slab[256 * 64];   // input, XOR-swizzled rows
    __shared__ __align__(16) short Ws[2 * 64 * 32];  // weight tap [kc][dl][i32]

    for (int u = tid; u < 2048; u += 256) {
        const int row = u >> 3;             // 0..255
        const int i8  = (u & 7) * 8;        // channel offset
        const int gt  = t0 - 64 + row;
        float4 a = {0.f, 0.f, 0.f, 0.f}, c4 = {0.f, 0.f, 0.f, 0.f};
        if (gt >= 0 && gt < T_) {
            const float* p = hin + ((size_t)(b * T_ + gt) * D_ + g * 64 + i8);
            a  = *(const float4*)p;
            c4 = *(const float4*)(p + 4);
        }
        ushort8 r;
        r[0] = f2b(a.x);  r[1] = f2b(a.y);  r[2] = f2b(a.z);  r[3] = f2b(a.w);
        r[4] = f2b(c4.x); r[5] = f2b(c4.y); r[6] = f2b(c4.z); r[7] = f2b(c4.w);
        const int byte = (row * 128 + i8 * 2) ^ ((row & 7) << 4);
        *(ushort8*)((char*)slab + byte) = r;
    }

    floatx4 acc[4][2] = {};

    for (int tap = 0; tap < 128; ++tap) {
        {
            const int row = w * 16 + lr;    // 0..63 (dl)
            const __hip_bfloat16* s0 = wg + (size_t)(g * 64 + row) * 8192 + tap * 64 + lc;
            __builtin_amdgcn_global_load_lds(
                (__attribute__((address_space(1))) void*)(uintptr_t)s0,
                (__attribute__((address_space(3))) void*)(uint32_t)(uintptr_t)&Ws[row * 32 + lc],
                16, 0, 0);
            __builtin_amdgcn_global_load_lds(
                (__attribute__((address_space(1))) void*)(uintptr_t)(s0 + 32),
                (__attribute__((address_space(3))) void*)(uint32_t)(uintptr_t)&Ws[2048 + row * 32 + lc],
                16, 0, 0);
        }
        __syncthreads();

        short8 af[4][2], bfr[2][2];
#pragma unroll
        for (int mi = 0; mi < 4; ++mi)
#pragma unroll
            for (int kc = 0; kc < 2; ++kc) {
                const int row  = wm + mi * 16 + fr + tap;    // slab row (<= 254)
                const int byte = (row * 128 + (kc * 32 + fk) * 2) ^ ((row & 7) << 4);
                af[mi][kc] = *(const short8*)((const char*)slab + byte);
            }
#pragma unroll
        for (int ni = 0; ni < 2; ++ni)
#pragma unroll
            for (int kc = 0; kc < 2; ++kc)
                bfr[ni][kc] = *(const short8*)&Ws[kc * 2048 + (wn + ni * 16 + fr) * 32 + fk];
#pragma unroll
        for (int mi = 0; mi < 4; ++mi)
#pragma unroll
            for (int ni = 0; ni < 2; ++ni)
#pragma unroll
                for (int kc = 0; kc < 2; ++kc)
                    acc[mi][ni] = __builtin_amdgcn_mfma_f32_16x16x32_bf16(
                        af[mi][kc], bfr[ni][kc], acc[mi][ni], 0, 0, 0);
        __syncthreads();
    }

    const int er = (lane >> 4) * 4;
    const int ec = lane & 15;
#pragma unroll
    for (int ni = 0; ni < 2; ++ni) {
        const int col = g * 64 + wn + ni * 16 + ec;
        const float bsv = bias[col];
#pragma unroll
        for (int mi = 0; mi < 4; ++mi) {
#pragma unroll
            for (int r = 0; r < 4; ++r) {
                const int t = t0 + wm + mi * 16 + er + r;
                const float rm = y_mask[b * T_ + t];
                const size_t idx = (size_t)(b * T_ + t) * D_ + col;
                hout[idx] = hin[idx] + gelu_f(acc[mi][ni][r] + bsv) * rm;
            }
        }
    }
}

// ---------------------------------------------------------------------------
// LayerNorm over D (in-place fp32), optional rowmask, optional bf16 shadow out
// ---------------------------------------------------------------------------
__global__ __launch_bounds__(256)
void ln_kernel(float* __restrict__ X, const float* __restrict__ g,
               const float* __restrict__ bt, const float* __restrict__ rowmask,
               __hip_bfloat16* __restrict__ outbf)
{
    const int m = blockIdx.x;
    const int tid = threadIdx.x;
    const int d = tid * 4;
    float* p = X + (size_t)m * D_ + d;
    float4 v = *(const float4*)p;
    float s  = v.x + v.y + v.z + v.w;
    float s2 = v.x * v.x + v.y * v.y + v.z * v.z + v.w * v.w;
#pragma unroll
    for (int off = 32; off; off >>= 1) {
        s  += __shfl_down(s, off);
        s2 += __shfl_down(s2, off);
    }
    __shared__ float rs[4], rs2[4];
    int wid = tid >> 6;
    if ((tid & 63) == 0) { rs[wid] = s; rs2[wid] = s2; }
    __syncthreads();
    s  = rs[0] + rs[1] + rs[2] + rs[3];
    s2 = rs2[0] + rs2[1] + rs2[2] + rs2[3];
    float mean = s * (1.f / D_);
    float var  = s2 * (1.f / D_) - mean * mean;
    float inv  = rsqrtf(var + 1e-5f);
    float rm = rowmask ? rowmask[m] : 1.f;
    float4 gg = *(const float4*)(g + d);
    float4 bb = *(const float4*)(bt + d);
    float4 o;
    o.x = ((v.x - mean) * inv * gg.x + bb.x) * rm;
    o.y = ((v.y - mean) * inv * gg.y + bb.y) * rm;
    o.z = ((v.z - mean) * inv * gg.z + bb.z) * rm;
    o.w = ((v.w - mean) * inv * gg.w + bb.w) * rm;
    *(float4*)p = o;
    if (outbf) {
        __hip_bfloat16* q = outbf + (size_t)m * D_ + d;
        q[0] = __float2bfloat16(o.x);
        q[1] = __float2bfloat16(o.y);
        q[2] = __float2bfloat16(o.z);
        q[3] = __float2bfloat16(o.w);
    }
}

// ---------------------------------------------------------------------------
// Pack q/k/v biases into one 3072-float vector
// ---------------------------------------------------------------------------
__global__ __launch_bounds__(256)
void packb_kernel(const float* __restrict__ qb, const float* __restrict__ kb,
                  const float* __restrict__ vb, float* __restrict__ out)
{
    int i = blockIdx.x * 256 + threadIdx.x;
    if (i >= 3 * D_) return;
    float v = (i < D_) ? qb[i] : (i < 2 * D_ ? kb[i - D_] : vb[i - 2 * D_]);
    out[i] = v;
}

// ---------------------------------------------------------------------------
// Pad proj_out_w (80,1024) fp32 -> (128,1024) bf16 (rows 80..127 zero)
// ---------------------------------------------------------------------------
__global__ __launch_bounds__(256)
void wpad_kernel(const float* __restrict__ w, __hip_bfloat16* __restrict__ wp)
{
    int i = blockIdx.x * 256 + threadIdx.x;   // 128*128 units of 8 elems
    if (i >= 128 * 128) return;
    int col = (i & 127) * 8;
    int row = i >> 7;
    ushort8 r;
#pragma unroll
    for (int j = 0; j < 8; ++j) r[j] = 0;
    if (row < NF_) {
        const float* s = w + (size_t)row * D_ + col;
        float4 a = *(const float4*)s;
        float4 b = *(const float4*)(s + 4);
        r[0] = f2b(a.x); r[1] = f2b(a.y); r[2] = f2b(a.z); r[3] = f2b(a.w);
        r[4] = f2b(b.x); r[5] = f2b(b.y); r[6] = f2b(b.z); r[7] = f2b(b.w);
    }
    *(ushort8*)((unsigned short*)wp + (size_t)row * D_ + col) = r;
}

// ---------------------------------------------------------------------------
// MFMA flash attention on fused QKV buffer (row stride 3*D, Q at 0, K at D,
// V at 2D). One (b,h) per block, 128 queries/block, 4 waves x 32 q-rows.
// KV tiles of 64. 0.125 Q-scale applied to scores in fp32.
// Swizzle rule everywhere: byte ^= ((row&7)<<4) on 128-byte rows.
// ---------------------------------------------------------------------------
__global__ __launch_bounds__(256)
void attn_mfma_kernel(const __hip_bfloat16* __restrict__ QKV,
                      const float* __restrict__ y_mask,
                      __hip_bfloat16* __restrict__ O)
{
    const int tid  = threadIdx.x;
    const int lane = tid & 63;
    const int w    = tid >> 6;
    const int q0   = blockIdx.x * 128;
    const int h    = blockIdx.y;
    const int b    = blockIdx.z;
    const float slope = exp2f(-0.5f * (float)(h + 1));
    const int LDQ = 3 * D_;

    __shared__ __align__(16) short Ks[64 * 64];        // [kv][d]  swizzled
    __shared__ __align__(16) short Vt[64 * 64];        // [d][kv]  swizzled
    __shared__ __align__(16) short Ps[4 * 32 * 64];    // per-wave [q][kv] swizzled

    const int g   = lane >> 4;        // 0..3
    const int l15 = lane & 15;
    const int er  = g * 4;            // C-layout row base
    const int ec  = l15;              // C-layout col
    const int wq  = w * 32;           // wave's q offset within block

    // Q fragments (A-layout: row = lane&15, elems = (lane>>4)*8 ..)
    short8 qf[2][2];
#pragma unroll
    for (int m = 0; m < 2; ++m)
#pragma unroll
        for (int kc = 0; kc < 2; ++kc) {
            const size_t off = ((size_t)(b * T_ + q0 + wq + m * 16 + l15) * LDQ)
                             + h * DH + kc * 32 + g * 8;
            qf[m][kc] = *(const short8*)(QKV + off);
        }

    floatx4 oacc[2][4] = {};
    float m_st[2][4], l_st[2][4];
#pragma unroll
    for (int m = 0; m < 2; ++m)
#pragma unroll
        for (int r = 0; r < 4; ++r) { m_st[m][r] = -1e30f; l_st[m][r] = 0.f; }

    short* Pw = &Ps[w * 32 * 64];

    for (int kt = 0; kt < T_; kt += 64) {
        __syncthreads();
        // ---- stage K tile: linear LDS dest, pre-swizzled global source ----
#pragma unroll
        for (int j = 0; j < 2; ++j) {
            const int kv = w * 16 + j * 8 + (lane >> 3);
            const int c  = lane & 7;
            const int sw = ((lane >> 3) & 7) << 4;          // (kv&7)<<4
            const __hip_bfloat16* src = QKV + ((size_t)(b * T_ + kt + kv) * LDQ + D_ + h * DH)
                                          + ((((c * 16) ^ sw)) >> 1);
            __builtin_amdgcn_global_load_lds(
                (__attribute__((address_space(1))) void*)(uintptr_t)src,
                (__attribute__((address_space(3))) void*)(uint32_t)(uintptr_t)&Ks[(w * 16 + j * 8) * 64],
                16, 0, 0);
        }
        // ---- stage V transposed: Vt[d][kv], packed pair writes ----
        {
            const int kv0 = (tid & 31) * 2;
            const int d0  = (tid >> 5) * 8;
            ushort8 va  = *(const ushort8*)(QKV + ((size_t)(b * T_ + kt + kv0    ) * LDQ + 2 * D_ + h * DH + d0));
            ushort8 vb8 = *(const ushort8*)(QKV + ((size_t)(b * T_ + kt + kv0 + 1) * LDQ + 2 * D_ + h * DH + d0));
#pragma unroll
            for (int j = 0; j < 8; ++j) {
                const int d = d0 + j;
                const int byte = ((d * 128 + kv0 * 2) ^ ((d & 7) << 4));
                unsigned int pk = (unsigned int)va[j] | ((unsigned int)vb8[j] << 16);
                *(unsigned int*)((char*)Vt + byte) = pk;
            }
        }
        __syncthreads();

        // ---- QK^T: S (32q x 64kv) per wave ----
        floatx4 sacc[2][4] = {};
#pragma unroll
        for (int kc = 0; kc < 2; ++kc) {
            short8 kf[4];
#pragma unroll
            for (int n = 0; n < 4; ++n) {
                const int kv = n * 16 + l15;
                const int byte = ((kv * 128 + (kc * 32 + g * 8) * 2) ^ ((kv & 7) << 4));
                kf[n] = *(const short8*)((const char*)Ks + byte);
            }
#pragma unroll
            for (int m = 0; m < 2; ++m)
#pragma unroll
                for (int n = 0; n < 4; ++n)
                    sacc[m][n] = __builtin_amdgcn_mfma_f32_16x16x32_bf16(
                        qf[m][kc], kf[n], sacc[m][n], 0, 0, 0);
        }

        float ymv[4];
#pragma unroll
        for (int n = 0; n < 4; ++n)
            ymv[n] = (1.f - y_mask[b * T_ + kt + n * 16 + ec]) * (-1e9f);

        // ---- bias + online softmax (row across 16 lanes, shfl_xor reduce) ----
#pragma unroll
        for (int m = 0; m < 2; ++m) {
#pragma unroll
            for (int r = 0; r < 4; ++r) {
                const float qgf = (float)(q0 + wq + m * 16 + er + r);
                float sv[4];
                float rowmax = -1e30f;
#pragma unroll
                for (int n = 0; n < 4; ++n) {
                    const float kgf = (float)(kt + n * 16 + ec);
                    float s = sacc[m][n][r] * 0.125f - slope * fabsf(qgf - kgf) + ymv[n];
                    sv[n] = s;
                    rowmax = fmaxf(rowmax, s);
                }
#pragma unroll
                for (int off = 1; off < 16; off <<= 1)
                    rowmax = fmaxf(rowmax, __shfl_xor(rowmax, off));
                const float mn   = fmaxf(m_st[m][r], rowmax);
                const float corr = __expf(m_st[m][r] - mn);
                m_st[m][r] = mn;
                float psum = 0.f;
#pragma unroll
                for (int n = 0; n < 4; ++n) {
                    float p = __expf(sv[n] - mn);
                    psum += p;
                    sacc[m][n][r] = p;
                }
#pragma unroll
                for (int off = 1; off < 16; off <<= 1)
                    psum += __shfl_xor(psum, off);
                l_st[m][r] = l_st[m][r] * corr + psum;
#pragma unroll
                for (int n = 0; n < 4; ++n)
                    oacc[m][n][r] *= corr;
            }
        }

        // ---- P -> bf16 -> per-wave swizzled LDS ----
#pragma unroll
        for (int m = 0; m < 2; ++m)
#pragma unroll
            for (int n = 0; n < 4; ++n)
#pragma unroll
                for (int r = 0; r < 4; ++r) {
                    const int ql = m * 16 + er + r;
                    const int kv = n * 16 + ec;
                    const int byte = ((ql * 128 + kv * 2) ^ ((ql & 7) << 4));
                    *(unsigned short*)((char*)Pw + byte) = f2b(sacc[m][n][r]);
                }

        // ---- PV: O += P @ V ----
#pragma unroll
        for (int kc = 0; kc < 2; ++kc) {
            short8 pf[2], vf[4];
#pragma unroll
            for (int m = 0; m < 2; ++m) {
                const int ql = m * 16 + l15;
                const int byte = ((ql * 128 + (kc * 32 + g * 8) * 2) ^ ((ql & 7) << 4));
                pf[m] = *(const short8*)((const char*)Pw + byte);
            }
#pragma unroll
            for (int n = 0; n < 4; ++n) {
                const int d = n * 16 + l15;
                const int byte = ((d * 128 + (kc * 32 + g * 8) * 2) ^ ((d & 7) << 4));
                vf[n] = *(const short8*)((const char*)Vt + byte);
            }
#pragma unroll
            for (int m = 0; m < 2; ++m)
#pragma unroll
                for (int n = 0; n < 4; ++n)
                    oacc[m][n] = __builtin_amdgcn_mfma_f32_16x16x32_bf16(
                        pf[m], vf[n], oacc[m][n], 0, 0, 0);
        }
    }

    // ---- epilogue: O * (1/l) -> bf16 ----
#pragma unroll
    for (int m = 0; m < 2; ++m) {
#pragma unroll
        for (int r = 0; r < 4; ++r) {
            const float inv = 1.f / l_st[m][r];
            const int qg = q0 + wq + m * 16 + er + r;
#pragma unroll
            for (int n = 0; n < 4; ++n) {
                O[((size_t)(b * T_ + qg) * D_) + h * DH + n * 16 + ec] =
                    __float2bfloat16(oacc[m][n][r] * inv);
            }
        }
    }
}

// ---------------------------------------------------------------------------
__global__ __launch_bounds__(256)
void outtrans_kernel(const float* __restrict__ tmp, const float* __restrict__ y_mask,
                     const float* __restrict__ pob, float* __restrict__ out)
{
    int e = blockIdx.x * 256 + threadIdx.x;
    if (e >= B_ * NF_ * T_) return;
    int t = e & 1023;
    int f = (e >> 10) % NF_;
    int b = e / (NF_ * T_);
    out[e] = (tmp[(size_t)(b * T_ + t) * 128 + f] + pob[f]) * y_mask[b * T_ + t];
}

// ---------------------------------------------------------------------------
static void cvt(const float* w, __hip_bfloat16* dst, size_t n, hipStream_t stream)
{
    int n8 = (int)(n / 8);
    f2b_kernel<<<(n8 + 255) / 256, 256, 0, stream>>>(w, dst, n8);
}

extern "C" void kernel_launch(void* const* d_in, const int* in_sizes, int n_in,
                              void* d_out, int out_size, void* d_ws, size_t ws_size,
                              hipStream_t stream)
{
    const float* x          = (const float*)d_in[0];
    const float* mu         = (const float*)d_in[1];
    const int*   tokens     = (const int*)  d_in[2];
    const float* t_in       = (const float*)d_in[3];
    const float* y_mask     = (const float*)d_in[4];
    const float* emb        = (const float*)d_in[5];
    const float* proj_in_w  = (const float*)d_in[6];
    const float* proj_in_b  = (const float*)d_in[7];
    const float* posconv_w  = (const float*)d_in[8];
    const float* posconv_b  = (const float*)d_in[9];
    const float* ln0_g      = (const float*)d_in[10];
    const float* ln0_b      = (const float*)d_in[11];
    const float* qw         = (const float*)d_in[12];
    const float* qb         = (const float*)d_in[13];
    const float* kw         = (const float*)d_in[14];
    const float* kb         = (const float*)d_in[15];
    const float* vw         = (const float*)d_in[16];
    const float* vb         = (const float*)d_in[17];
    const float* ow         = (const float*)d_in[18];
    const float* ob         = (const float*)d_in[19];
    const float* ln1_g      = (const float*)d_in[20];
    const float* ln1_b      = (const float*)d_in[21];
    const float* ffw1       = (const float*)d_in[22];
    const float* ffb1       = (const float*)d_in[23];
    const float* ffw2       = (const float*)d_in[24];
    const float* ffb2       = (const float*)d_in[25];
    const float* ln2_g      = (const float*)d_in[26];
    const float* ln2_b      = (const float*)d_in[27];
    const float* skw        = (const float*)d_in[28];
    const float* skb        = (const float*)d_in[29];
    const float* pow_       = (const float*)d_in[30];
    const float* pob        = (const float*)d_in[31];

    const size_t MB = (size_t)1 << 20;
    char* wsb = (char*)d_ws;
    float*          hA     = (float*)(wsb + 0);            // 16 MB
    float*          hB     = (float*)(wsb + 16 * MB);      // 16 MB
    __hip_bfloat16* hbfA   = (__hip_bfloat16*)(wsb + 32 * MB);   // 8 MB
    __hip_bfloat16* skipbf = (__hip_bfloat16*)(wsb + 40 * MB);   // 32 MB (4 x 8)
    __hip_bfloat16* qkv_bf = (__hip_bfloat16*)(wsb + 72 * MB);   // 24 MB fused QKV
    __hip_bfloat16* o_bf   = (__hip_bfloat16*)(wsb + 96 * MB);   // 8 MB
    __hip_bfloat16* ff_bf  = (__hip_bfloat16*)(wsb + 104 * MB);  // 32 MB
    __hip_bfloat16* wslab  = (__hip_bfloat16*)(wsb + 136 * MB);  // 8 MB (weights)
    float*          biasq  = (float*)(wsb + 144 * MB);           // 12 KB qkv bias
    __hip_bfloat16* hbfB   = (__hip_bfloat16*)(wsb + 152 * MB);  // 8 MB
    // aliases (disjoint lifetimes)
    __hip_bfloat16* wgbf   = (__hip_bfloat16*)(wsb + 104 * MB);  // 16 MB, stem only
    __hip_bfloat16* xin_bf = qkv_bf;                        // 3.4 MB, stem only
    float*          tmpO   = (float*)(wsb + 72 * MB);      // 2 MB, tail only

    const size_t MD = (size_t)M_ * D_;
    const size_t DD = (size_t)D_ * D_;

    dim3 gD(D_ / 128, M_ / 64);     // (8, 64)  BM=64
    dim3 gQKV(3 * D_ / 128, M_ / 64); // (24, 64) BM=64
    dim3 gF(F_ / 128, M_ / 128);    // (32, 32) BM=128

    // ---- stem ----
    xin_kernel<<<M_, 256, 0, stream>>>(x, mu, tokens, emb, xin_bf);
    cvt(proj_in_w, wslab, (size_t)D_ * CIN, stream);
    mfma_gemm<0, 0, 64><<<gD, 256, 0, stream>>>(xin_bf, nullptr, CIN, wslab, proj_in_b,
                                                nullptr, nullptr, hA, nullptr, M_, D_, CIN, 1.f);
    temb_kernel<<<M_, 256, 0, stream>>>(hA, t_in, y_mask);

    wgtrans_kernel<<<4096, 256, 0, stream>>>(posconv_w, wgbf, 0);
    convmfma_kernel<<<dim3(8, 16, 4), 256, 0, stream>>>(hA, hB, wgbf, posconv_b, y_mask);
    wgtrans_kernel<<<4096, 256, 0, stream>>>(posconv_w, wgbf, 1);
    convmfma_kernel<<<dim3(8, 16, 4), 256, 0, stream>>>(hB, hA, wgbf, posconv_b + D_, y_mask);

    ln_kernel<<<M_, 256, 0, stream>>>(hA, ln0_g, ln0_b, nullptr, hbfA);

    float* h = hA;  float* hx = hB;
    __hip_bfloat16* hbf = hbfA;  __hip_bfloat16* hbf_alt = hbfB;

    for (int i = 0; i < L_; ++i) {
        if (i >= L_ / 2) {
            cvt(skw + (size_t)(i - 4) * D_ * 2 * D_, wslab, (size_t)D_ * 2 * D_, stream);
            mfma_gemm<0, 2, 64><<<gD, 256, 0, stream>>>(hbf, skipbf + (size_t)(7 - i) * MD, D_,
                wslab, skb + (size_t)(i - 4) * D_, nullptr, nullptr,
                hx, hbf_alt, M_, D_, 2 * D_, 1.f);
            { float* t0 = h; h = hx; hx = t0; }
            { __hip_bfloat16* t0 = hbf; hbf = hbf_alt; hbf_alt = t0; }
        }
        // fused QKV projection (N = 3072)
        cvt(qw + (size_t)i * DD, wslab,           DD, stream);
        cvt(kw + (size_t)i * DD, wslab + DD,      DD, stream);
        cvt(vw + (size_t)i * DD, wslab + 2 * DD,  DD, stream);
        packb_kernel<<<12, 256, 0, stream>>>(qb + (size_t)i * D_, kb + (size_t)i * D_,
                                             vb + (size_t)i * D_, biasq);
        mfma_gemm<0, 1, 64><<<gQKV, 256, 0, stream>>>(hbf, nullptr, D_, wslab, biasq,
            nullptr, nullptr, nullptr, qkv_bf, M_, 3 * D_, D_, 1.f);

        attn_mfma_kernel<<<dim3(T_ / 128, H_, B_), 256, 0, stream>>>(qkv_bf, y_mask, o_bf);

        cvt(ow + (size_t)i * DD, wslab, DD, stream);
        mfma_gemm<0, 0, 64><<<gD, 256, 0, stream>>>(o_bf, nullptr, D_, wslab, ob + (size_t)i * D_,
            h, y_mask, hx, nullptr, M_, D_, D_, 1.f);
        { float* t0 = h; h = hx; hx = t0; }

        ln_kernel<<<M_, 256, 0, stream>>>(h, ln1_g + (size_t)i * D_, ln1_b + (size_t)i * D_,
                                          nullptr, hbf);

        cvt(ffw1 + (size_t)i * F_ * D_, wslab, (size_t)F_ * D_, stream);
        mfma_gemm<1, 1, 128><<<gF, 256, 0, stream>>>(hbf, nullptr, D_, wslab, ffb1 + (size_t)i * F_,
            nullptr, nullptr, nullptr, ff_bf, M_, F_, D_, 1.f);
        cvt(ffw2 + (size_t)i * D_ * F_, wslab, (size_t)D_ * F_, stream);
        mfma_gemm<0, 0, 64><<<gD, 256, 0, stream>>>(ff_bf, nullptr, F_, wslab, ffb2 + (size_t)i * D_,
            h, y_mask, hx, nullptr, M_, D_, F_, 1.f);
        { float* t0 = h; h = hx; hx = t0; }

        ln_kernel<<<M_, 256, 0, stream>>>(h, ln2_g + (size_t)i * D_, ln2_b + (size_t)i * D_,
                                          y_mask, hbf);

        if (i < L_ / 2) {
            hipMemcpyAsync(skipbf + (size_t)i * MD, hbf, MD * sizeof(__hip_bfloat16),
                           hipMemcpyDeviceToDevice, stream);
        }
    }

    // ---- tail: proj_out via MFMA on padded (128,1024) weight panel ----
    wpad_kernel<<<64, 256, 0, stream>>>(pow_, wslab);
    mfma_gemm<0, 0, 64><<<dim3(1, M_ / 64), 256, 0, stream>>>(hbf, nullptr, D_, wslab,
        nullptr, nullptr, nullptr, tmpO, nullptr, M_, 128, D_, 1.f);
    outtrans_kernel<<<(B_ * NF_ * T_ + 255) / 256, 256, 0, stream>>>(tmpO, y_mask, pob, (float*)d_out);
}